// Round 2
// baseline (4099.837 us; speedup 1.0000x reference)
//
#include <hip/hip_runtime.h>
#include <cstdint>
#include <cstddef>

typedef _Float16 half8 __attribute__((ext_vector_type(8)));
typedef _Float16 half4 __attribute__((ext_vector_type(4)));
typedef float floatx4 __attribute__((ext_vector_type(4)));

#define BATCH 256
#define NCHK 512
#define NVAR 1024
#define EDGE 3072

// ---- check MLP tiling ----
#define KC    96
#define NT1C  26     // hidden 388 -> 416 -> 26 col-tiles of 16
#define KS1C  3      // GEMM1 K = 96 -> 3 chunks of 32
#define NT2C  6      // out 96 -> 6 tiles of 16 (3 b128 pairs)
#define HHC   13     // hidden tiles per wave (split-hidden: 2 waves/row-group)
// ---- var MLP tiling ----
#define NT1V  13     // hidden 196 -> 208 -> 13 col-tiles of 16
#define KS1V  2      // GEMM1 K 49 -> 64 -> 2 chunks of 32
#define NT2V  4      // out 49 -> 64 -> 4 tiles of 16 (2 b128 pairs)

__device__ __forceinline__ float gelu_f(float x) {
  // exact gelu via A&S 7.1.26 erf approx, |err(erf)| < 1.5e-7
  float ax = fabsf(x) * 0.70710678118654752440f;
  float t  = 1.0f / fmaf(0.3275911f, ax, 1.0f);
  float p  = t * (0.254829592f + t * (-0.284496736f + t * (1.421413741f +
             t * (-1.453152027f + t * 1.061405429f))));
  float e  = __expf(-ax * ax);
  float erfv = fmaf(-p, e, 1.0f);        // >= 0 for all ax >= 0
  float s  = copysignf(erfv, x);         // v_bfi, replaces cmp+cndmask
  float hx = 0.5f * x;
  return fmaf(hx, s, hx);                // 0.5*x*(1+s)
}

__device__ __forceinline__ half4 lo4(half8 v) {
  return __builtin_shufflevector(v, v, 0, 1, 2, 3);
}
__device__ __forceinline__ half4 hi4(half8 v) {
  return __builtin_shufflevector(v, v, 4, 5, 6, 7);
}

// W1 packs: K32 A-operand fragments (16x16x32): frag[(s*NT1+nt)*64+l][j] =
//   W[k = s*32 + (l>>4)*8 + j][n = nt*16 + (l&15)]
// W2 packs: K16 A-operand fragments (16x16x16) in nt-PAIRS (b128 loads):
//   frag[(ht*NP + np)*64+l][j] = W[k = ht*16 + (l>>4)*4 + (j&3)]
//                                 [n = (2np + (j>>2))*16 + (l&15)]
__global__ void pack_kernel(const float* __restrict__ cW1, const float* __restrict__ cb1,
                            const float* __restrict__ cW2, const float* __restrict__ cb2,
                            const float* __restrict__ vW1, const float* __restrict__ vb1,
                            const float* __restrict__ vW2, const float* __restrict__ vb2,
                            _Float16* __restrict__ w1c, _Float16* __restrict__ w2c,
                            _Float16* __restrict__ w1v, _Float16* __restrict__ w2v,
                            float* __restrict__ b1c, float* __restrict__ w96c,
                            float* __restrict__ b2c, float* __restrict__ b1v,
                            float* __restrict__ b2v)
{
  int id = blockIdx.x * 256 + threadIdx.x;
  const int S0 = KS1C * NT1C * 64;   // 4992  (half8)
  const int S1 = NT1C * 3 * 64;      // 4992  (half8 = paired half4)
  const int S2 = KS1V * NT1V * 64;   // 1664  (half8)
  const int S3 = NT1V * 2 * 64;      // 1664  (half8 = paired half4)
  if (id < S0) {
    int s = id / (NT1C * 64), rem = id % (NT1C * 64), nt = rem / 64, l = rem % 64;
    int q = l >> 4, n = nt * 16 + (l & 15);
    half8 v;
    #pragma unroll
    for (int j = 0; j < 8; ++j) {
      int k = s * 32 + q * 8 + j;
      float x = (n < 388) ? cW1[k * 388 + n] : 0.0f;
      v[j] = (_Float16)x;
    }
    *(half8*)(w1c + (size_t)id * 8) = v;
    return;
  }
  id -= S0;
  if (id < S1) {
    int ht = id / (3 * 64), rem = id % (3 * 64), np = rem / 64, l = rem % 64;
    int q = l >> 4, c = l & 15;
    half8 v;
    #pragma unroll
    for (int j = 0; j < 8; ++j) {
      int k = ht * 16 + q * 4 + (j & 3);
      int n = (2 * np + (j >> 2)) * 16 + c;
      float x = (k < 388) ? cW2[k * 96 + n] : 0.0f;
      v[j] = (_Float16)x;
    }
    *(half8*)(w2c + (size_t)id * 8) = v;
    return;
  }
  id -= S1;
  if (id < S2) {
    int s = id / (NT1V * 64), rem = id % (NT1V * 64), nt = rem / 64, l = rem % 64;
    int q = l >> 4, n = nt * 16 + (l & 15);
    half8 v;
    #pragma unroll
    for (int j = 0; j < 8; ++j) {
      int k = s * 32 + q * 8 + j;                        // row 48 = prior row
      float x = (k < 49 && n < 196) ? vW1[k * 196 + n] : 0.0f;
      v[j] = (_Float16)x;
    }
    *(half8*)(w1v + (size_t)id * 8) = v;
    return;
  }
  id -= S2;
  if (id < S3) {
    int ht = id / (2 * 64), rem = id % (2 * 64), np = rem / 64, l = rem % 64;
    int q = l >> 4, c = l & 15;
    half8 v;
    #pragma unroll
    for (int j = 0; j < 8; ++j) {
      int k = ht * 16 + q * 4 + (j & 3);
      int n = (2 * np + (j >> 2)) * 16 + c;
      float x = (k < 196 && n < 49) ? vW2[k * 49 + n] : 0.0f;
      v[j] = (_Float16)x;
    }
    *(half8*)(w2v + (size_t)id * 8) = v;
    return;
  }
  id -= S3;
  if (id < 416) { b1c[id]  = (id < 388) ? cb1[id] : 0.0f; return; }
  id -= 416;
  if (id < 416) { w96c[id] = (id < 388) ? cW1[96 * 388 + id] : 0.0f; return; }
  id -= 416;
  if (id < 96)  { b2c[id]  = cb2[id]; return; }
  id -= 96;
  if (id < 208) { b1v[id]  = (id < 196) ? vb1[id] : 0.0f; return; }
  id -= 208;
  if (id < 64)  { b2v[id]  = (id < 49) ? vb2[id] : 0.0f; return; }
}

__global__ void init_kernel(const int* __restrict__ perm, const float* __restrict__ prior,
                            _Float16* __restrict__ Mc)
{
  int t = blockIdx.x * 256 + threadIdx.x;   // t < BATCH*EDGE
  int b = t / EDGE, k = t - b * EDGE;
  int e = perm[k];
  _Float16* dst = Mc + ((size_t)b * EDGE + e) * 16;
  half8 z  = {0,0,0,0,0,0,0,0};
  half8 z0 = z;
  z0[0] = (_Float16)prior[k / 3];
  *(half8*)dst = z0;
  *(half8*)(dst + 8) = z;
}

// Check-node MLP, split-hidden: block = 64 rows = 2 pairs x 2 waves.
// Within a pair, wave h owns hidden tiles [13h, 13h+13): GEMM1 N-chunks and
// GEMM2 K-chunks. Partial acc2 reduced through 12 KB LDS at the end.
// Grid = 2048 blocks -> 8 blocks/CU -> 8 waves/SIMD (vs 4 before).
__global__ __launch_bounds__(256, 8) void kernelC(
    const _Float16* __restrict__ Mc, const int* __restrict__ synd,
    _Float16* __restrict__ Yc,
    const _Float16* __restrict__ W1p, const _Float16* __restrict__ W2p,
    const float* __restrict__ b1, const float* __restrict__ w96,
    const float* __restrict__ b2)
{
  __shared__ floatx4 red[2][3][2][64];   // [pair][ntSlot][rg][lane] = 12 KiB
  const int tid = threadIdx.x, w = tid >> 6, l = tid & 63;
  const int q = l >> 4, c = l & 15;
  const int p = w >> 1, hh = w & 1;
  const int r0 = blockIdx.x * 64 + p * 32;

  // Mc fragments (B-operand: lane holds batch-row n = l&15, k = q*8+j)
  half8 mb[2][3];
  float sg[2];
  #pragma unroll
  for (int rg = 0; rg < 2; ++rg) {
    const _Float16* Arow = Mc + (size_t)(r0 + rg * 16 + c) * KC;
    #pragma unroll
    for (int ks = 0; ks < 3; ++ks)
      mb[rg][ks] = *(const half8*)(Arow + ks * 32 + q * 8);
    sg[rg] = 1.0f - 2.0f * (float)synd[r0 + rg * 16 + c];
  }

  floatx4 acc2[2][6];
  #pragma unroll
  for (int rg = 0; rg < 2; ++rg)
    #pragma unroll
    for (int nt = 0; nt < 6; ++nt)
      acc2[rg][nt] = (floatx4){0.f, 0.f, 0.f, 0.f};

  const half8* W1f = (const half8*)W1p;
  const half8* W2f = (const half8*)W2p;

  const int htBase = hh * HHC;
  #pragma unroll 2
  for (int i = 0; i < HHC; ++i) {
    const int ht = htBase + i;
    half8 wa0 = W1f[(0 * NT1C + ht) * 64 + l];
    half8 wa1 = W1f[(1 * NT1C + ht) * 64 + l];
    half8 wa2 = W1f[(2 * NT1C + ht) * 64 + l];
    half8 wp0 = W2f[(ht * 3 + 0) * 64 + l];   // nt 0,1
    half8 wp1 = W2f[(ht * 3 + 1) * 64 + l];   // nt 2,3
    half8 wp2 = W2f[(ht * 3 + 2) * 64 + l];   // nt 4,5
    floatx4 bia = *(const floatx4*)(b1  + ht * 16 + q * 4);
    floatx4 wsg = *(const floatx4*)(w96 + ht * 16 + q * 4);
    #pragma unroll
    for (int rg = 0; rg < 2; ++rg) {
      floatx4 a = {0.f, 0.f, 0.f, 0.f};
      a = __builtin_amdgcn_mfma_f32_16x16x32_f16(wa0, mb[rg][0], a, 0, 0, 0);
      a = __builtin_amdgcn_mfma_f32_16x16x32_f16(wa1, mb[rg][1], a, 0, 0, 0);
      a = __builtin_amdgcn_mfma_f32_16x16x32_f16(wa2, mb[rg][2], a, 0, 0, 0);
      half4 h;
      #pragma unroll
      for (int r = 0; r < 4; ++r)
        h[r] = (_Float16)gelu_f(a[r] + bia[r] + sg[rg] * wsg[r]);
      acc2[rg][0] = __builtin_amdgcn_mfma_f32_16x16x16f16(lo4(wp0), h, acc2[rg][0], 0, 0, 0);
      acc2[rg][1] = __builtin_amdgcn_mfma_f32_16x16x16f16(hi4(wp0), h, acc2[rg][1], 0, 0, 0);
      acc2[rg][2] = __builtin_amdgcn_mfma_f32_16x16x16f16(lo4(wp1), h, acc2[rg][2], 0, 0, 0);
      acc2[rg][3] = __builtin_amdgcn_mfma_f32_16x16x16f16(hi4(wp1), h, acc2[rg][3], 0, 0, 0);
      acc2[rg][4] = __builtin_amdgcn_mfma_f32_16x16x16f16(lo4(wp2), h, acc2[rg][4], 0, 0, 0);
      acc2[rg][5] = __builtin_amdgcn_mfma_f32_16x16x16f16(hi4(wp2), h, acc2[rg][5], 0, 0, 0);
    }
  }

  // Cross-wave reduction within each pair + split epilogue.
  if (hh) {
    #pragma unroll
    for (int rg = 0; rg < 2; ++rg)
      #pragma unroll
      for (int nt = 0; nt < 3; ++nt)
        red[p][nt][rg][l] = acc2[rg][nt];
  }
  __syncthreads();
  if (!hh) {
    #pragma unroll
    for (int rg = 0; rg < 2; ++rg) {
      const size_t row = (size_t)(r0 + rg * 16 + c);
      #pragma unroll
      for (int nt = 0; nt < 3; ++nt) {
        floatx4 v = acc2[rg][nt] + red[p][nt][rg][l];
        floatx4 bia = *(const floatx4*)(b2 + nt * 16 + q * 4);
        half4 yy;
        #pragma unroll
        for (int r = 0; r < 4; ++r)
          yy[r] = (_Float16)((v[r] + bia[r]) * sg[rg]);
        *(half4*)(Yc + row * 96 + nt * 16 + q * 4) = yy;
      }
      #pragma unroll
      for (int nt = 3; nt < 6; ++nt)
        red[p][nt - 3][rg][l] = acc2[rg][nt];   // same addrs this lane just read
    }
  }
  __syncthreads();
  if (hh) {
    #pragma unroll
    for (int rg = 0; rg < 2; ++rg) {
      const size_t row = (size_t)(r0 + rg * 16 + c);
      #pragma unroll
      for (int nt = 3; nt < 6; ++nt) {
        floatx4 v = acc2[rg][nt] + red[p][nt - 3][rg][l];
        floatx4 bia = *(const floatx4*)(b2 + nt * 16 + q * 4);
        half4 yy;
        #pragma unroll
        for (int r = 0; r < 4; ++r)
          yy[r] = (_Float16)((v[r] + bia[r]) * sg[rg]);
        *(half4*)(Yc + row * 96 + nt * 16 + q * 4) = yy;
      }
    }
  }
}

// Variable-node MLP, register-direct GEMM1->GEMM2 (no LDS). Gathers Yc via
// perm (B-frags), scatters Mc via perm in packed 8B chunks, emits llr.
__global__ __launch_bounds__(256, 8) void kernelV(
    const _Float16* __restrict__ Yc, const int* __restrict__ perm,
    const float* __restrict__ prior,
    _Float16* __restrict__ Mc, float* __restrict__ outp,
    const _Float16* __restrict__ W1p, const _Float16* __restrict__ W2p,
    const float* __restrict__ b1, const float* __restrict__ b2)
{
  const int tid = threadIdx.x, w = tid >> 6, l = tid & 63;
  const int q = l >> 4, c = l & 15;
  const int r0 = blockIdx.x * 128 + w * 32;
  const int b  = r0 >> 10;
  const int v0 = r0 & 1023;
  const size_t yb = (size_t)b * EDGE;

  // Xv^T fragments: lane holds var-row n = l&15, k = q*8+j (K=64: 48 msgs + prior + pad)
  half8 mb[2][2];
  #pragma unroll
  for (int rg = 0; rg < 2; ++rg) {
    int v = v0 + rg * 16 + c;
    int e0 = perm[3 * v + (q >> 1)];
    mb[rg][0] = *(const half8*)(Yc + (yb + e0) * 16 + (q & 1) * 8);
    half8 m1 = {0,0,0,0,0,0,0,0};
    if (q < 2) {
      int e2 = perm[3 * v + 2];
      m1 = *(const half8*)(Yc + (yb + e2) * 16 + q * 8);
    } else if (q == 2) {
      m1[0] = (_Float16)prior[v];
    }
    mb[rg][1] = m1;
  }

  floatx4 acc2[2][4];
  #pragma unroll
  for (int rg = 0; rg < 2; ++rg)
    #pragma unroll
    for (int nt = 0; nt < 4; ++nt)
      acc2[rg][nt] = (floatx4){0.f, 0.f, 0.f, 0.f};

  const half8* W1f = (const half8*)W1p;
  const half8* W2f = (const half8*)W2p;

  #pragma unroll 2
  for (int ht = 0; ht < NT1V; ++ht) {
    half8 wa0 = W1f[(0 * NT1V + ht) * 64 + l];
    half8 wa1 = W1f[(1 * NT1V + ht) * 64 + l];
    half8 wp0 = W2f[(ht * 2 + 0) * 64 + l];   // nt 0,1
    half8 wp1 = W2f[(ht * 2 + 1) * 64 + l];   // nt 2,3
    floatx4 bia = *(const floatx4*)(b1 + ht * 16 + q * 4);
    #pragma unroll
    for (int rg = 0; rg < 2; ++rg) {
      floatx4 a = {0.f, 0.f, 0.f, 0.f};
      a = __builtin_amdgcn_mfma_f32_16x16x32_f16(wa0, mb[rg][0], a, 0, 0, 0);
      a = __builtin_amdgcn_mfma_f32_16x16x32_f16(wa1, mb[rg][1], a, 0, 0, 0);
      half4 h;
      #pragma unroll
      for (int r = 0; r < 4; ++r)
        h[r] = (_Float16)gelu_f(a[r] + bia[r]);
      acc2[rg][0] = __builtin_amdgcn_mfma_f32_16x16x16f16(lo4(wp0), h, acc2[rg][0], 0, 0, 0);
      acc2[rg][1] = __builtin_amdgcn_mfma_f32_16x16x16f16(hi4(wp0), h, acc2[rg][1], 0, 0, 0);
      acc2[rg][2] = __builtin_amdgcn_mfma_f32_16x16x16f16(lo4(wp1), h, acc2[rg][2], 0, 0, 0);
      acc2[rg][3] = __builtin_amdgcn_mfma_f32_16x16x16f16(hi4(wp1), h, acc2[rg][3], 0, 0, 0);
    }
  }

  const float bllr = b2[48];
  #pragma unroll
  for (int rg = 0; rg < 2; ++rg) {
    int v = v0 + rg * 16 + c;
    #pragma unroll
    for (int nt = 0; nt < 3; ++nt) {
      int pe = perm[3 * v + nt];
      floatx4 bia = *(const floatx4*)(b2 + nt * 16 + q * 4);
      half4 yy;
      #pragma unroll
      for (int r = 0; r < 4; ++r)
        yy[r] = (_Float16)(acc2[rg][nt][r] + bia[r]);
      *(half4*)(Mc + (yb + pe) * 16 + q * 4) = yy;
    }
    if (q == 0)
      outp[r0 + rg * 16 + c] = acc2[rg][3][0] + bllr;
  }
}

extern "C" void kernel_launch(void* const* d_in, const int* in_sizes, int n_in,
                              void* d_out, int out_size, void* d_ws, size_t ws_size,
                              hipStream_t stream)
{
  const int*   synd  = (const int*)d_in[0];
  const float* prior = (const float*)d_in[2];
  const int*   perm  = (const int*)d_in[3];
  const float* cW1 = (const float*)d_in[4];
  const float* cb1 = (const float*)d_in[5];
  const float* cW2 = (const float*)d_in[6];
  const float* cb2 = (const float*)d_in[7];
  const float* vW1 = (const float*)d_in[8];
  const float* vb1 = (const float*)d_in[9];
  const float* vW2 = (const float*)d_in[10];
  const float* vb2 = (const float*)d_in[11];
  float* outp = (float*)d_out;
  const int T = out_size / (BATCH * NVAR);

  char* p = (char*)d_ws;
  _Float16* Mc  = (_Float16*)p; p += (size_t)BATCH * EDGE * 16 * 2;
  _Float16* Yc  = (_Float16*)p; p += (size_t)BATCH * EDGE * 16 * 2;
  _Float16* w1c = (_Float16*)p; p += (size_t)KS1C * NT1C * 64 * 8 * 2;
  _Float16* w2c = (_Float16*)p; p += (size_t)NT1C * 3 * 64 * 8 * 2;
  _Float16* w1v = (_Float16*)p; p += (size_t)KS1V * NT1V * 64 * 8 * 2;
  _Float16* w2v = (_Float16*)p; p += (size_t)NT1V * 2 * 64 * 8 * 2;
  float* b1c  = (float*)p; p += 416 * 4;
  float* w96c = (float*)p; p += 416 * 4;
  float* b2c  = (float*)p; p += 96 * 4;
  float* b1v  = (float*)p; p += 208 * 4;
  float* b2v  = (float*)p; p += 64 * 4;

  const int packN = KS1C * NT1C * 64 + NT1C * 3 * 64 + KS1V * NT1V * 64 +
                    NT1V * 2 * 64 + 416 + 416 + 96 + 208 + 64;   // 14512
  pack_kernel<<<(packN + 255) / 256, 256, 0, stream>>>(
      cW1, cb1, cW2, cb2, vW1, vb1, vW2, vb2,
      w1c, w2c, w1v, w2v, b1c, w96c, b2c, b1v, b2v);
  init_kernel<<<(BATCH * EDGE) / 256, 256, 0, stream>>>(perm, prior, Mc);

  for (int t = 0; t < T; ++t) {
    kernelC<<<(BATCH * NCHK) / 64, 256, 0, stream>>>(
        Mc, synd, Yc, w1c, w2c, b1c, w96c, b2c);
    kernelV<<<(BATCH * NVAR) / 128, 256, 0, stream>>>(
        Yc, perm, prior, Mc, outp + (size_t)t * BATCH * NVAR, w1v, w2v, b1v, b2v);
  }
}

// Round 3
// 699.553 us; speedup vs baseline: 5.8606x; 5.8606x over previous
//
#include <hip/hip_runtime.h>
#include <cstdint>
#include <cstddef>

typedef _Float16 half8 __attribute__((ext_vector_type(8)));
typedef _Float16 half4 __attribute__((ext_vector_type(4)));
typedef float floatx4 __attribute__((ext_vector_type(4)));

#define BATCH 256
#define NCHK 512
#define NVAR 1024
#define EDGE 3072

// ---- check MLP tiling ----
#define KC    96
#define NT1C  26     // hidden 388 -> 416 -> 26 col-tiles of 16
#define KS1C  3      // GEMM1 K = 96 -> 3 chunks of 32
#define NT2C  6      // out 96 -> 6 tiles of 16 (3 b128 pairs)
// ---- var MLP tiling ----
#define NT1V  13     // hidden 196 -> 208 -> 13 col-tiles of 16
#define KS1V  2      // GEMM1 K 49 -> 64 -> 2 chunks of 32
#define NT2V  4      // out 49 -> 64 -> 4 tiles of 16 (2 b128 pairs)

__device__ __forceinline__ float gelu_f(float x) {
  // exact gelu via A&S 7.1.26 erf approx, |err(erf)| < 1.5e-7
  float ax = fabsf(x) * 0.70710678118654752440f;
  float t  = 1.0f / fmaf(0.3275911f, ax, 1.0f);
  float p  = t * (0.254829592f + t * (-0.284496736f + t * (1.421413741f +
             t * (-1.453152027f + t * 1.061405429f))));
  float e  = __expf(-ax * ax);
  float erfv = fmaf(-p, e, 1.0f);        // >= 0 for all ax >= 0
  float s  = copysignf(erfv, x);         // v_bfi, replaces cmp+cndmask
  float hx = 0.5f * x;
  return fmaf(hx, s, hx);                // 0.5*x*(1+s)
}

__device__ __forceinline__ half4 lo4(half8 v) {
  return __builtin_shufflevector(v, v, 0, 1, 2, 3);
}
__device__ __forceinline__ half4 hi4(half8 v) {
  return __builtin_shufflevector(v, v, 4, 5, 6, 7);
}

// W1 packs: K32 A-operand fragments (16x16x32): frag[(s*NT1+nt)*64+l][j] =
//   W[k = s*32 + (l>>4)*8 + j][n = nt*16 + (l&15)]
// W2 packs: K16 A-operand fragments (16x16x16) in nt-PAIRS (b128 loads):
//   frag[(ht*NP + np)*64+l][j] = W[k = ht*16 + (l>>4)*4 + (j&3)]
//                                 [n = (2np + (j>>2))*16 + (l&15)]
__global__ void pack_kernel(const float* __restrict__ cW1, const float* __restrict__ cb1,
                            const float* __restrict__ cW2, const float* __restrict__ cb2,
                            const float* __restrict__ vW1, const float* __restrict__ vb1,
                            const float* __restrict__ vW2, const float* __restrict__ vb2,
                            _Float16* __restrict__ w1c, _Float16* __restrict__ w2c,
                            _Float16* __restrict__ w1v, _Float16* __restrict__ w2v,
                            float* __restrict__ b1c, float* __restrict__ w96c,
                            float* __restrict__ b2c, float* __restrict__ b1v,
                            float* __restrict__ b2v)
{
  int id = blockIdx.x * 256 + threadIdx.x;
  const int S0 = KS1C * NT1C * 64;   // 4992  (half8)
  const int S1 = NT1C * 3 * 64;      // 4992  (half8 = paired half4)
  const int S2 = KS1V * NT1V * 64;   // 1664  (half8)
  const int S3 = NT1V * 2 * 64;      // 1664  (half8 = paired half4)
  if (id < S0) {
    int s = id / (NT1C * 64), rem = id % (NT1C * 64), nt = rem / 64, l = rem % 64;
    int q = l >> 4, n = nt * 16 + (l & 15);
    half8 v;
    #pragma unroll
    for (int j = 0; j < 8; ++j) {
      int k = s * 32 + q * 8 + j;
      float x = (n < 388) ? cW1[k * 388 + n] : 0.0f;
      v[j] = (_Float16)x;
    }
    *(half8*)(w1c + (size_t)id * 8) = v;
    return;
  }
  id -= S0;
  if (id < S1) {
    int ht = id / (3 * 64), rem = id % (3 * 64), np = rem / 64, l = rem % 64;
    int q = l >> 4, c = l & 15;
    half8 v;
    #pragma unroll
    for (int j = 0; j < 8; ++j) {
      int k = ht * 16 + q * 4 + (j & 3);
      int n = (2 * np + (j >> 2)) * 16 + c;
      float x = (k < 388) ? cW2[k * 96 + n] : 0.0f;
      v[j] = (_Float16)x;
    }
    *(half8*)(w2c + (size_t)id * 8) = v;
    return;
  }
  id -= S1;
  if (id < S2) {
    int s = id / (NT1V * 64), rem = id % (NT1V * 64), nt = rem / 64, l = rem % 64;
    int q = l >> 4, n = nt * 16 + (l & 15);
    half8 v;
    #pragma unroll
    for (int j = 0; j < 8; ++j) {
      int k = s * 32 + q * 8 + j;                        // row 48 = prior row
      float x = (k < 49 && n < 196) ? vW1[k * 196 + n] : 0.0f;
      v[j] = (_Float16)x;
    }
    *(half8*)(w1v + (size_t)id * 8) = v;
    return;
  }
  id -= S2;
  if (id < S3) {
    int ht = id / (2 * 64), rem = id % (2 * 64), np = rem / 64, l = rem % 64;
    int q = l >> 4, c = l & 15;
    half8 v;
    #pragma unroll
    for (int j = 0; j < 8; ++j) {
      int k = ht * 16 + q * 4 + (j & 3);
      int n = (2 * np + (j >> 2)) * 16 + c;
      float x = (k < 196 && n < 49) ? vW2[k * 49 + n] : 0.0f;
      v[j] = (_Float16)x;
    }
    *(half8*)(w2v + (size_t)id * 8) = v;
    return;
  }
  id -= S3;
  if (id < 416) { b1c[id]  = (id < 388) ? cb1[id] : 0.0f; return; }
  id -= 416;
  if (id < 416) { w96c[id] = (id < 388) ? cW1[96 * 388 + id] : 0.0f; return; }
  id -= 416;
  if (id < 96)  { b2c[id]  = cb2[id]; return; }
  id -= 96;
  if (id < 208) { b1v[id]  = (id < 196) ? vb1[id] : 0.0f; return; }
  id -= 208;
  if (id < 64)  { b2v[id]  = (id < 49) ? vb2[id] : 0.0f; return; }
}

__global__ void init_kernel(const int* __restrict__ perm, const float* __restrict__ prior,
                            _Float16* __restrict__ Mc)
{
  int t = blockIdx.x * 256 + threadIdx.x;   // t < BATCH*EDGE
  int b = t / EDGE, k = t - b * EDGE;
  int e = perm[k];
  _Float16* dst = Mc + ((size_t)b * EDGE + e) * 16;
  half8 z  = {0,0,0,0,0,0,0,0};
  half8 z0 = z;
  z0[0] = (_Float16)prior[k / 3];
  *(half8*)dst = z0;
  *(half8*)(dst + 8) = z;
}

// Check-node MLP, 16 rows/wave (register diet: ~24 acc + 12 frag VGPRs ->
// target 5 waves/SIMD; round-2 lesson: NEVER cap launch_bounds below the
// natural footprint — (256,5) caps at 102 regs, natural ~90, no spills).
// Register-direct GEMM1 -> gelu -> GEMM2 (K16 MFMA), zero LDS.
__global__ __launch_bounds__(256, 5) void kernelC(
    const _Float16* __restrict__ Mc, const int* __restrict__ synd,
    _Float16* __restrict__ Yc,
    const _Float16* __restrict__ W1p, const _Float16* __restrict__ W2p,
    const float* __restrict__ b1, const float* __restrict__ w96,
    const float* __restrict__ b2)
{
  const int tid = threadIdx.x, w = tid >> 6, l = tid & 63;
  const int q = l >> 4, c = l & 15;
  const int r0 = blockIdx.x * 64 + w * 16;

  // Mc fragment (B-operand: lane holds batch-row n = l&15, k = q*8+j)
  half8 mb[3];
  const _Float16* Arow = Mc + (size_t)(r0 + c) * KC;
  #pragma unroll
  for (int ks = 0; ks < 3; ++ks)
    mb[ks] = *(const half8*)(Arow + ks * 32 + q * 8);
  const float sg = 1.0f - 2.0f * (float)synd[r0 + c];

  floatx4 acc2[6];
  #pragma unroll
  for (int nt = 0; nt < 6; ++nt)
    acc2[nt] = (floatx4){0.f, 0.f, 0.f, 0.f};

  const half8* W1f = (const half8*)W1p;
  const half8* W2f = (const half8*)W2p;

  #pragma unroll 1
  for (int ht = 0; ht < NT1C; ++ht) {
    half8 wa0 = W1f[(0 * NT1C + ht) * 64 + l];
    half8 wa1 = W1f[(1 * NT1C + ht) * 64 + l];
    half8 wa2 = W1f[(2 * NT1C + ht) * 64 + l];
    half8 wp0 = W2f[(ht * 3 + 0) * 64 + l];   // out tiles 0,1
    half8 wp1 = W2f[(ht * 3 + 1) * 64 + l];   // out tiles 2,3
    half8 wp2 = W2f[(ht * 3 + 2) * 64 + l];   // out tiles 4,5
    floatx4 bia = *(const floatx4*)(b1  + ht * 16 + q * 4);
    floatx4 wsg = *(const floatx4*)(w96 + ht * 16 + q * 4);
    floatx4 a = {0.f, 0.f, 0.f, 0.f};
    a = __builtin_amdgcn_mfma_f32_16x16x32_f16(wa0, mb[0], a, 0, 0, 0);
    a = __builtin_amdgcn_mfma_f32_16x16x32_f16(wa1, mb[1], a, 0, 0, 0);
    a = __builtin_amdgcn_mfma_f32_16x16x32_f16(wa2, mb[2], a, 0, 0, 0);
    half4 h;
    #pragma unroll
    for (int r = 0; r < 4; ++r)
      h[r] = (_Float16)gelu_f(a[r] + bia[r] + sg * wsg[r]);
    acc2[0] = __builtin_amdgcn_mfma_f32_16x16x16f16(lo4(wp0), h, acc2[0], 0, 0, 0);
    acc2[1] = __builtin_amdgcn_mfma_f32_16x16x16f16(hi4(wp0), h, acc2[1], 0, 0, 0);
    acc2[2] = __builtin_amdgcn_mfma_f32_16x16x16f16(lo4(wp1), h, acc2[2], 0, 0, 0);
    acc2[3] = __builtin_amdgcn_mfma_f32_16x16x16f16(hi4(wp1), h, acc2[3], 0, 0, 0);
    acc2[4] = __builtin_amdgcn_mfma_f32_16x16x16f16(lo4(wp2), h, acc2[4], 0, 0, 0);
    acc2[5] = __builtin_amdgcn_mfma_f32_16x16x16f16(hi4(wp2), h, acc2[5], 0, 0, 0);
  }

  const size_t row = (size_t)(r0 + c);
  #pragma unroll
  for (int nt = 0; nt < 6; ++nt) {
    floatx4 bia = *(const floatx4*)(b2 + nt * 16 + q * 4);
    half4 yy;
    #pragma unroll
    for (int r = 0; r < 4; ++r)
      yy[r] = (_Float16)((acc2[nt][r] + bia[r]) * sg);
    *(half4*)(Yc + row * 96 + nt * 16 + q * 4) = yy;
  }
}

// Variable-node MLP, 16 vars/wave (~16 acc + 8 frag VGPRs -> target 7-8
// waves/SIMD). Gathers Yc via perm (B-frags), scatters Mc via perm in packed
// 8B chunks, emits llr (out col 48).
__global__ __launch_bounds__(256, 6) void kernelV(
    const _Float16* __restrict__ Yc, const int* __restrict__ perm,
    const float* __restrict__ prior,
    _Float16* __restrict__ Mc, float* __restrict__ outp,
    const _Float16* __restrict__ W1p, const _Float16* __restrict__ W2p,
    const float* __restrict__ b1, const float* __restrict__ b2)
{
  const int tid = threadIdx.x, w = tid >> 6, l = tid & 63;
  const int q = l >> 4, c = l & 15;
  const int r0 = blockIdx.x * 64 + w * 16;
  const int b  = r0 >> 10;
  const int v0 = r0 & 1023;
  const size_t yb = (size_t)b * EDGE;

  // Xv^T fragment: lane holds var-row n = l&15, k = q*8+j (K=64: 48 msgs + prior + pad)
  half8 mb[2];
  {
    int v = v0 + c;
    int e0 = perm[3 * v + (q >> 1)];
    mb[0] = *(const half8*)(Yc + (yb + e0) * 16 + (q & 1) * 8);
    half8 m1 = {0,0,0,0,0,0,0,0};
    if (q < 2) {
      int e2 = perm[3 * v + 2];
      m1 = *(const half8*)(Yc + (yb + e2) * 16 + q * 8);
    } else if (q == 2) {
      m1[0] = (_Float16)prior[v];
    }
    mb[1] = m1;
  }

  floatx4 acc2[4];
  #pragma unroll
  for (int nt = 0; nt < 4; ++nt)
    acc2[nt] = (floatx4){0.f, 0.f, 0.f, 0.f};

  const half8* W1f = (const half8*)W1p;
  const half8* W2f = (const half8*)W2p;

  #pragma unroll 1
  for (int ht = 0; ht < NT1V; ++ht) {
    half8 wa0 = W1f[(0 * NT1V + ht) * 64 + l];
    half8 wa1 = W1f[(1 * NT1V + ht) * 64 + l];
    half8 wp0 = W2f[(ht * 2 + 0) * 64 + l];   // out tiles 0,1
    half8 wp1 = W2f[(ht * 2 + 1) * 64 + l];   // out tiles 2,3
    floatx4 bia = *(const floatx4*)(b1 + ht * 16 + q * 4);
    floatx4 a = {0.f, 0.f, 0.f, 0.f};
    a = __builtin_amdgcn_mfma_f32_16x16x32_f16(wa0, mb[0], a, 0, 0, 0);
    a = __builtin_amdgcn_mfma_f32_16x16x32_f16(wa1, mb[1], a, 0, 0, 0);
    half4 h;
    #pragma unroll
    for (int r = 0; r < 4; ++r)
      h[r] = (_Float16)gelu_f(a[r] + bia[r]);
    acc2[0] = __builtin_amdgcn_mfma_f32_16x16x16f16(lo4(wp0), h, acc2[0], 0, 0, 0);
    acc2[1] = __builtin_amdgcn_mfma_f32_16x16x16f16(hi4(wp0), h, acc2[1], 0, 0, 0);
    acc2[2] = __builtin_amdgcn_mfma_f32_16x16x16f16(lo4(wp1), h, acc2[2], 0, 0, 0);
    acc2[3] = __builtin_amdgcn_mfma_f32_16x16x16f16(hi4(wp1), h, acc2[3], 0, 0, 0);
  }

  const float bllr = b2[48];
  {
    int v = v0 + c;
    #pragma unroll
    for (int nt = 0; nt < 3; ++nt) {
      int pe = perm[3 * v + nt];
      floatx4 bia = *(const floatx4*)(b2 + nt * 16 + q * 4);
      half4 yy;
      #pragma unroll
      for (int r = 0; r < 4; ++r)
        yy[r] = (_Float16)(acc2[nt][r] + bia[r]);
      *(half4*)(Mc + (yb + pe) * 16 + q * 4) = yy;
    }
    if (q == 0)
      outp[r0 + c] = acc2[3][0] + bllr;
  }
}

extern "C" void kernel_launch(void* const* d_in, const int* in_sizes, int n_in,
                              void* d_out, int out_size, void* d_ws, size_t ws_size,
                              hipStream_t stream)
{
  const int*   synd  = (const int*)d_in[0];
  const float* prior = (const float*)d_in[2];
  const int*   perm  = (const int*)d_in[3];
  const float* cW1 = (const float*)d_in[4];
  const float* cb1 = (const float*)d_in[5];
  const float* cW2 = (const float*)d_in[6];
  const float* cb2 = (const float*)d_in[7];
  const float* vW1 = (const float*)d_in[8];
  const float* vb1 = (const float*)d_in[9];
  const float* vW2 = (const float*)d_in[10];
  const float* vb2 = (const float*)d_in[11];
  float* outp = (float*)d_out;
  const int T = out_size / (BATCH * NVAR);

  char* p = (char*)d_ws;
  _Float16* Mc  = (_Float16*)p; p += (size_t)BATCH * EDGE * 16 * 2;
  _Float16* Yc  = (_Float16*)p; p += (size_t)BATCH * EDGE * 16 * 2;
  _Float16* w1c = (_Float16*)p; p += (size_t)KS1C * NT1C * 64 * 8 * 2;
  _Float16* w2c = (_Float16*)p; p += (size_t)NT1C * 3 * 64 * 8 * 2;
  _Float16* w1v = (_Float16*)p; p += (size_t)KS1V * NT1V * 64 * 8 * 2;
  _Float16* w2v = (_Float16*)p; p += (size_t)NT1V * 2 * 64 * 8 * 2;
  float* b1c  = (float*)p; p += 416 * 4;
  float* w96c = (float*)p; p += 416 * 4;
  float* b2c  = (float*)p; p += 96 * 4;
  float* b1v  = (float*)p; p += 208 * 4;
  float* b2v  = (float*)p; p += 64 * 4;

  const int packN = KS1C * NT1C * 64 + NT1C * 3 * 64 + KS1V * NT1V * 64 +
                    NT1V * 2 * 64 + 416 + 416 + 96 + 208 + 64;   // 14512
  pack_kernel<<<(packN + 255) / 256, 256, 0, stream>>>(
      cW1, cb1, cW2, cb2, vW1, vb1, vW2, vb2,
      w1c, w2c, w1v, w2v, b1c, w96c, b2c, b1v, b2v);
  init_kernel<<<(BATCH * EDGE) / 256, 256, 0, stream>>>(perm, prior, Mc);

  for (int t = 0; t < T; ++t) {
    kernelC<<<(BATCH * NCHK) / 64, 256, 0, stream>>>(
        Mc, synd, Yc, w1c, w2c, b1c, w96c, b2c);
    kernelV<<<(BATCH * NVAR) / 64, 256, 0, stream>>>(
        Yc, perm, prior, Mc, outp + (size_t)t * BATCH * NVAR, w1v, w2v, b1v, b2v);
  }
}

// Round 4
// 688.287 us; speedup vs baseline: 5.9566x; 1.0164x over previous
//
#include <hip/hip_runtime.h>
#include <cstdint>
#include <cstddef>

typedef _Float16 half8 __attribute__((ext_vector_type(8)));
typedef _Float16 half4 __attribute__((ext_vector_type(4)));
typedef float floatx4 __attribute__((ext_vector_type(4)));

#define BATCH 256
#define NCHK 512
#define NVAR 1024
#define EDGE 3072

// ---- check MLP tiling ----
#define KC    96
#define NT1C  26     // hidden 388 -> 416 -> 26 col-tiles of 16
#define KS1C  3      // GEMM1 K = 96 -> 3 chunks of 32
#define NT2C  6      // out 96 -> 6 tiles of 16 (3 b128 pairs)
// ---- var MLP tiling ----
#define NT1V  13     // hidden 196 -> 208 -> 13 col-tiles of 16
#define KS1V  2      // GEMM1 K 49 -> 64 -> 2 chunks of 32
#define NT2V  4      // out 49 -> 64 -> 4 tiles of 16 (2 b128 pairs)

__device__ __forceinline__ float gelu_f(float x) {
  // exact gelu via A&S 7.1.26 erf approx, |err(erf)| < 1.5e-7 (table builder only)
  float ax = fabsf(x) * 0.70710678118654752440f;
  float t  = 1.0f / fmaf(0.3275911f, ax, 1.0f);
  float p  = t * (0.254829592f + t * (-0.284496736f + t * (1.421413741f +
             t * (-1.453152027f + t * 1.061405429f))));
  float e  = __expf(-ax * ax);
  float erfv = fmaf(-p, e, 1.0f);
  float s  = copysignf(erfv, x);
  float hx = 0.5f * x;
  return fmaf(hx, s, hx);
}

// PWL gelu: 1024 segments over [-8,8], node+slope in LDS (float2, ds_read_b64).
// |err| <= w^2/8 * max|gelu''| = (1/64)^2/8 * 0.8 ~ 2.4e-5 absolute.
// Out of range: h += max(t-tc,0)/64 -> exact h=x for x>8; h~0 for x<-8.
__device__ __forceinline__ float gelu_lut(const float2* __restrict__ tab, float x) {
  float t  = fmaf(x, 64.0f, 512.0f);
  float tc = fminf(fmaxf(t, 0.0f), 1023.0f);
  float tf = __builtin_truncf(tc);
  float fr = tc - tf;
  int idx  = (int)tf;
  float2 ns = tab[idx];
  float h  = fmaf(fr, ns.y, ns.x);
  return fmaf(fmaxf(t - tc, 0.0f), 0.015625f, h);
}

#define BUILD_TAB(tab)                                            \
  for (int k_ = threadIdx.x; k_ < 1024; k_ += 256) {              \
    float x_  = (k_ - 512) * 0.015625f;                           \
    float y0_ = gelu_f(x_);                                       \
    float y1_ = gelu_f(x_ + 0.015625f);                           \
    tab[k_] = make_float2(y0_, y1_ - y0_);                        \
  }                                                               \
  __syncthreads();

__device__ __forceinline__ half4 lo4(half8 v) {
  return __builtin_shufflevector(v, v, 0, 1, 2, 3);
}
__device__ __forceinline__ half4 hi4(half8 v) {
  return __builtin_shufflevector(v, v, 4, 5, 6, 7);
}

// W1 packs: K32 A-operand fragments (16x16x32): frag[(s*NT1+nt)*64+l][j] =
//   W[k = s*32 + (l>>4)*8 + j][n = nt*16 + (l&15)]
// W2 packs: K16 A-operand fragments (16x16x16) in nt-PAIRS (b128 loads):
//   frag[(ht*NP + np)*64+l][j] = W[k = ht*16 + (l>>4)*4 + (j&3)]
//                                 [n = (2np + (j>>2))*16 + (l&15)]
__global__ void pack_kernel(const float* __restrict__ cW1, const float* __restrict__ cb1,
                            const float* __restrict__ cW2, const float* __restrict__ cb2,
                            const float* __restrict__ vW1, const float* __restrict__ vb1,
                            const float* __restrict__ vW2, const float* __restrict__ vb2,
                            _Float16* __restrict__ w1c, _Float16* __restrict__ w2c,
                            _Float16* __restrict__ w1v, _Float16* __restrict__ w2v,
                            float* __restrict__ b1c, float* __restrict__ w96c,
                            float* __restrict__ b2c, float* __restrict__ b1v,
                            float* __restrict__ b2v)
{
  int id = blockIdx.x * 256 + threadIdx.x;
  const int S0 = KS1C * NT1C * 64;   // 4992  (half8)
  const int S1 = NT1C * 3 * 64;      // 4992  (half8 = paired half4)
  const int S2 = KS1V * NT1V * 64;   // 1664  (half8)
  const int S3 = NT1V * 2 * 64;      // 1664  (half8 = paired half4)
  if (id < S0) {
    int s = id / (NT1C * 64), rem = id % (NT1C * 64), nt = rem / 64, l = rem % 64;
    int q = l >> 4, n = nt * 16 + (l & 15);
    half8 v;
    #pragma unroll
    for (int j = 0; j < 8; ++j) {
      int k = s * 32 + q * 8 + j;
      float x = (n < 388) ? cW1[k * 388 + n] : 0.0f;
      v[j] = (_Float16)x;
    }
    *(half8*)(w1c + (size_t)id * 8) = v;
    return;
  }
  id -= S0;
  if (id < S1) {
    int ht = id / (3 * 64), rem = id % (3 * 64), np = rem / 64, l = rem % 64;
    int q = l >> 4, c = l & 15;
    half8 v;
    #pragma unroll
    for (int j = 0; j < 8; ++j) {
      int k = ht * 16 + q * 4 + (j & 3);
      int n = (2 * np + (j >> 2)) * 16 + c;
      float x = (k < 388) ? cW2[k * 96 + n] : 0.0f;
      v[j] = (_Float16)x;
    }
    *(half8*)(w2c + (size_t)id * 8) = v;
    return;
  }
  id -= S1;
  if (id < S2) {
    int s = id / (NT1V * 64), rem = id % (NT1V * 64), nt = rem / 64, l = rem % 64;
    int q = l >> 4, n = nt * 16 + (l & 15);
    half8 v;
    #pragma unroll
    for (int j = 0; j < 8; ++j) {
      int k = s * 32 + q * 8 + j;                        // row 48 = prior row
      float x = (k < 49 && n < 196) ? vW1[k * 196 + n] : 0.0f;
      v[j] = (_Float16)x;
    }
    *(half8*)(w1v + (size_t)id * 8) = v;
    return;
  }
  id -= S2;
  if (id < S3) {
    int ht = id / (2 * 64), rem = id % (2 * 64), np = rem / 64, l = rem % 64;
    int q = l >> 4, c = l & 15;
    half8 v;
    #pragma unroll
    for (int j = 0; j < 8; ++j) {
      int k = ht * 16 + q * 4 + (j & 3);
      int n = (2 * np + (j >> 2)) * 16 + c;
      float x = (k < 196 && n < 49) ? vW2[k * 49 + n] : 0.0f;
      v[j] = (_Float16)x;
    }
    *(half8*)(w2v + (size_t)id * 8) = v;
    return;
  }
  id -= S3;
  if (id < 416) { b1c[id]  = (id < 388) ? cb1[id] : 0.0f; return; }
  id -= 416;
  if (id < 416) { w96c[id] = (id < 388) ? cW1[96 * 388 + id] : 0.0f; return; }
  id -= 416;
  if (id < 96)  { b2c[id]  = cb2[id]; return; }
  id -= 96;
  if (id < 208) { b1v[id]  = (id < 196) ? vb1[id] : 0.0f; return; }
  id -= 208;
  if (id < 64)  { b2v[id]  = (id < 49) ? vb2[id] : 0.0f; return; }
}

__global__ void init_kernel(const int* __restrict__ perm, const float* __restrict__ prior,
                            _Float16* __restrict__ Mc)
{
  int t = blockIdx.x * 256 + threadIdx.x;   // t < BATCH*EDGE
  int b = t / EDGE, k = t - b * EDGE;
  int e = perm[k];
  _Float16* dst = Mc + ((size_t)b * EDGE + e) * 16;
  half8 z  = {0,0,0,0,0,0,0,0};
  half8 z0 = z;
  z0[0] = (_Float16)prior[k / 3];
  *(half8*)dst = z0;
  *(half8*)(dst + 8) = z;
}

// Check-node MLP, 16 rows/wave, register-direct GEMM1 -> LUT-gelu -> GEMM2.
// bias + sg*w96 folded into the GEMM1 MFMA C-operand init (saves VALU).
// gelu via 8KB LDS PWL table (no rcp/exp trans ops — they were the pipe floor:
// VALUBusy pinned ~55% across rg=1/2/4 and occupancy 30-46%).
__global__ __launch_bounds__(256, 5) void kernelC(
    const _Float16* __restrict__ Mc, const int* __restrict__ synd,
    _Float16* __restrict__ Yc,
    const _Float16* __restrict__ W1p, const _Float16* __restrict__ W2p,
    const float* __restrict__ b1, const float* __restrict__ w96,
    const float* __restrict__ b2)
{
  __shared__ float2 tab[1024];
  BUILD_TAB(tab)

  const int tid = threadIdx.x, w = tid >> 6, l = tid & 63;
  const int q = l >> 4, c = l & 15;
  const int r0 = blockIdx.x * 64 + w * 16;

  // Mc fragment (B-operand: lane holds batch-row n = l&15, k = q*8+j)
  half8 mb[3];
  const _Float16* Arow = Mc + (size_t)(r0 + c) * KC;
  #pragma unroll
  for (int ks = 0; ks < 3; ++ks)
    mb[ks] = *(const half8*)(Arow + ks * 32 + q * 8);
  const float sg = 1.0f - 2.0f * (float)synd[r0 + c];

  floatx4 acc2[6];
  #pragma unroll
  for (int nt = 0; nt < 6; ++nt)
    acc2[nt] = (floatx4){0.f, 0.f, 0.f, 0.f};

  const half8* W1f = (const half8*)W1p;
  const half8* W2f = (const half8*)W2p;

  #pragma unroll 1
  for (int ht = 0; ht < NT1C; ++ht) {
    half8 wa0 = W1f[(0 * NT1C + ht) * 64 + l];
    half8 wa1 = W1f[(1 * NT1C + ht) * 64 + l];
    half8 wa2 = W1f[(2 * NT1C + ht) * 64 + l];
    half8 wp0 = W2f[(ht * 3 + 0) * 64 + l];   // out tiles 0,1
    half8 wp1 = W2f[(ht * 3 + 1) * 64 + l];   // out tiles 2,3
    half8 wp2 = W2f[(ht * 3 + 2) * 64 + l];   // out tiles 4,5
    floatx4 bia = *(const floatx4*)(b1  + ht * 16 + q * 4);
    floatx4 wsg = *(const floatx4*)(w96 + ht * 16 + q * 4);
    floatx4 a;
    #pragma unroll
    for (int r = 0; r < 4; ++r)
      a[r] = fmaf(sg, wsg[r], bia[r]);       // C-operand init = bias + sg*w96
    a = __builtin_amdgcn_mfma_f32_16x16x32_f16(wa0, mb[0], a, 0, 0, 0);
    a = __builtin_amdgcn_mfma_f32_16x16x32_f16(wa1, mb[1], a, 0, 0, 0);
    a = __builtin_amdgcn_mfma_f32_16x16x32_f16(wa2, mb[2], a, 0, 0, 0);
    half4 h;
    #pragma unroll
    for (int r = 0; r < 4; ++r)
      h[r] = (_Float16)gelu_lut(tab, a[r]);
    acc2[0] = __builtin_amdgcn_mfma_f32_16x16x16f16(lo4(wp0), h, acc2[0], 0, 0, 0);
    acc2[1] = __builtin_amdgcn_mfma_f32_16x16x16f16(hi4(wp0), h, acc2[1], 0, 0, 0);
    acc2[2] = __builtin_amdgcn_mfma_f32_16x16x16f16(lo4(wp1), h, acc2[2], 0, 0, 0);
    acc2[3] = __builtin_amdgcn_mfma_f32_16x16x16f16(hi4(wp1), h, acc2[3], 0, 0, 0);
    acc2[4] = __builtin_amdgcn_mfma_f32_16x16x16f16(lo4(wp2), h, acc2[4], 0, 0, 0);
    acc2[5] = __builtin_amdgcn_mfma_f32_16x16x16f16(hi4(wp2), h, acc2[5], 0, 0, 0);
  }

  const size_t row = (size_t)(r0 + c);
  #pragma unroll
  for (int nt = 0; nt < 6; ++nt) {
    floatx4 bia = *(const floatx4*)(b2 + nt * 16 + q * 4);
    half4 yy;
    #pragma unroll
    for (int r = 0; r < 4; ++r)
      yy[r] = (_Float16)((acc2[nt][r] + bia[r]) * sg);
    *(half4*)(Yc + row * 96 + nt * 16 + q * 4) = yy;
  }
}

// Variable-node MLP, 16 vars/wave, LUT-gelu, bias as GEMM1 C-operand init
// (the loaded b1 vector IS the init — zero extra VALU).
__global__ __launch_bounds__(256, 6) void kernelV(
    const _Float16* __restrict__ Yc, const int* __restrict__ perm,
    const float* __restrict__ prior,
    _Float16* __restrict__ Mc, float* __restrict__ outp,
    const _Float16* __restrict__ W1p, const _Float16* __restrict__ W2p,
    const float* __restrict__ b1, const float* __restrict__ b2)
{
  __shared__ float2 tab[1024];
  BUILD_TAB(tab)

  const int tid = threadIdx.x, w = tid >> 6, l = tid & 63;
  const int q = l >> 4, c = l & 15;
  const int r0 = blockIdx.x * 64 + w * 16;
  const int b  = r0 >> 10;
  const int v0 = r0 & 1023;
  const size_t yb = (size_t)b * EDGE;

  // Xv^T fragment: lane holds var-row n = l&15, k = q*8+j (K=64: 48 msgs + prior + pad)
  half8 mb[2];
  {
    int v = v0 + c;
    int e0 = perm[3 * v + (q >> 1)];
    mb[0] = *(const half8*)(Yc + (yb + e0) * 16 + (q & 1) * 8);
    half8 m1 = {0,0,0,0,0,0,0,0};
    if (q < 2) {
      int e2 = perm[3 * v + 2];
      m1 = *(const half8*)(Yc + (yb + e2) * 16 + q * 8);
    } else if (q == 2) {
      m1[0] = (_Float16)prior[v];
    }
    mb[1] = m1;
  }

  floatx4 acc2[4];
  #pragma unroll
  for (int nt = 0; nt < 4; ++nt)
    acc2[nt] = (floatx4){0.f, 0.f, 0.f, 0.f};

  const half8* W1f = (const half8*)W1p;
  const half8* W2f = (const half8*)W2p;

  #pragma unroll 1
  for (int ht = 0; ht < NT1V; ++ht) {
    half8 wa0 = W1f[(0 * NT1V + ht) * 64 + l];
    half8 wa1 = W1f[(1 * NT1V + ht) * 64 + l];
    half8 wp0 = W2f[(ht * 2 + 0) * 64 + l];   // out tiles 0,1
    half8 wp1 = W2f[(ht * 2 + 1) * 64 + l];   // out tiles 2,3
    floatx4 a = *(const floatx4*)(b1 + ht * 16 + q * 4);   // C-init = bias
    a = __builtin_amdgcn_mfma_f32_16x16x32_f16(wa0, mb[0], a, 0, 0, 0);
    a = __builtin_amdgcn_mfma_f32_16x16x32_f16(wa1, mb[1], a, 0, 0, 0);
    half4 h;
    #pragma unroll
    for (int r = 0; r < 4; ++r)
      h[r] = (_Float16)gelu_lut(tab, a[r]);
    acc2[0] = __builtin_amdgcn_mfma_f32_16x16x16f16(lo4(wp0), h, acc2[0], 0, 0, 0);
    acc2[1] = __builtin_amdgcn_mfma_f32_16x16x16f16(hi4(wp0), h, acc2[1], 0, 0, 0);
    acc2[2] = __builtin_amdgcn_mfma_f32_16x16x16f16(lo4(wp1), h, acc2[2], 0, 0, 0);
    acc2[3] = __builtin_amdgcn_mfma_f32_16x16x16f16(hi4(wp1), h, acc2[3], 0, 0, 0);
  }

  const float bllr = b2[48];
  {
    int v = v0 + c;
    #pragma unroll
    for (int nt = 0; nt < 3; ++nt) {
      int pe = perm[3 * v + nt];
      floatx4 bia = *(const floatx4*)(b2 + nt * 16 + q * 4);
      half4 yy;
      #pragma unroll
      for (int r = 0; r < 4; ++r)
        yy[r] = (_Float16)(acc2[nt][r] + bia[r]);
      *(half4*)(Mc + (yb + pe) * 16 + q * 4) = yy;
    }
    if (q == 0)
      outp[r0 + c] = acc2[3][0] + bllr;
  }
}

extern "C" void kernel_launch(void* const* d_in, const int* in_sizes, int n_in,
                              void* d_out, int out_size, void* d_ws, size_t ws_size,
                              hipStream_t stream)
{
  const int*   synd  = (const int*)d_in[0];
  const float* prior = (const float*)d_in[2];
  const int*   perm  = (const int*)d_in[3];
  const float* cW1 = (const float*)d_in[4];
  const float* cb1 = (const float*)d_in[5];
  const float* cW2 = (const float*)d_in[6];
  const float* cb2 = (const float*)d_in[7];
  const float* vW1 = (const float*)d_in[8];
  const float* vb1 = (const float*)d_in[9];
  const float* vW2 = (const float*)d_in[10];
  const float* vb2 = (const float*)d_in[11];
  float* outp = (float*)d_out;
  const int T = out_size / (BATCH * NVAR);

  char* p = (char*)d_ws;
  _Float16* Mc  = (_Float16*)p; p += (size_t)BATCH * EDGE * 16 * 2;
  _Float16* Yc  = (_Float16*)p; p += (size_t)BATCH * EDGE * 16 * 2;
  _Float16* w1c = (_Float16*)p; p += (size_t)KS1C * NT1C * 64 * 8 * 2;
  _Float16* w2c = (_Float16*)p; p += (size_t)NT1C * 3 * 64 * 8 * 2;
  _Float16* w1v = (_Float16*)p; p += (size_t)KS1V * NT1V * 64 * 8 * 2;
  _Float16* w2v = (_Float16*)p; p += (size_t)NT1V * 2 * 64 * 8 * 2;
  float* b1c  = (float*)p; p += 416 * 4;
  float* w96c = (float*)p; p += 416 * 4;
  float* b2c  = (float*)p; p += 96 * 4;
  float* b1v  = (float*)p; p += 208 * 4;
  float* b2v  = (float*)p; p += 64 * 4;

  const int packN = KS1C * NT1C * 64 + NT1C * 3 * 64 + KS1V * NT1V * 64 +
                    NT1V * 2 * 64 + 416 + 416 + 96 + 208 + 64;   // 14512
  pack_kernel<<<(packN + 255) / 256, 256, 0, stream>>>(
      cW1, cb1, cW2, cb2, vW1, vb1, vW2, vb2,
      w1c, w2c, w1v, w2v, b1c, w96c, b2c, b1v, b2v);
  init_kernel<<<(BATCH * EDGE) / 256, 256, 0, stream>>>(perm, prior, Mc);

  for (int t = 0; t < T; ++t) {
    kernelC<<<(BATCH * NCHK) / 64, 256, 0, stream>>>(
        Mc, synd, Yc, w1c, w2c, b1c, w96c, b2c);
    kernelV<<<(BATCH * NVAR) / 64, 256, 0, stream>>>(
        Yc, perm, prior, Mc, outp + (size_t)t * BATCH * NVAR, w1v, w2v, b1v, b2v);
  }
}

// Round 6
// 624.477 us; speedup vs baseline: 6.5652x; 1.1022x over previous
//
#include <hip/hip_runtime.h>
#include <cstdint>
#include <cstddef>

typedef _Float16 half8 __attribute__((ext_vector_type(8)));
typedef _Float16 half4 __attribute__((ext_vector_type(4)));
typedef float floatx4 __attribute__((ext_vector_type(4)));

#define BATCH 256
#define NCHK 512
#define NVAR 1024
#define EDGE 3072

// ---- check MLP tiling ----
#define KC    96
#define NT1C  26     // hidden 388 -> 416 -> 26 col-tiles of 16
#define KS1C  3      // GEMM1 K = 96 -> 3 chunks of 32
#define NT2C  6      // out 96 -> 6 tiles of 16 (3 b128 pairs)
// ---- var MLP tiling ----
#define NT1V  13     // hidden 196 -> 208 -> 13 col-tiles of 16
#define KS1V  2      // GEMM1 K 49 -> 64 -> 2 chunks of 32
#define NT2V  4      // out 49 -> 64 -> 4 tiles of 16 (2 b128 pairs)

__device__ __forceinline__ float gelu_f(float x) {
  // exact gelu via A&S 7.1.26 erf approx, |err(erf)| < 1.5e-7 (table builder only)
  float ax = fabsf(x) * 0.70710678118654752440f;
  float t  = 1.0f / fmaf(0.3275911f, ax, 1.0f);
  float p  = t * (0.254829592f + t * (-0.284496736f + t * (1.421413741f +
             t * (-1.453152027f + t * 1.061405429f))));
  float e  = __expf(-ax * ax);
  float erfv = fmaf(-p, e, 1.0f);
  float s  = copysignf(erfv, x);
  float hx = 0.5f * x;
  return fmaf(hx, s, hx);
}

// PWL gelu: 1024 segments over [-8,8], node+slope in LDS (float2, ds_read_b64).
// |err| <= w^2/8 * max|gelu''| = (1/64)^2/8 * 0.8 ~ 2.4e-5 absolute.
// Out of range: h += max(t-tc,0)/64 -> exact h=x for x>8; h~0 for x<-8.
__device__ __forceinline__ float gelu_lut(const float2* __restrict__ tab, float x) {
  float t  = fmaf(x, 64.0f, 512.0f);
  float tc = fminf(fmaxf(t, 0.0f), 1023.0f);
  float tf = __builtin_truncf(tc);
  float fr = tc - tf;
  int idx  = (int)tf;
  float2 ns = tab[idx];
  float h  = fmaf(fr, ns.y, ns.x);
  return fmaf(fmaxf(t - tc, 0.0f), 0.015625f, h);
}

#define BUILD_TAB(tab)                                            \
  for (int k_ = threadIdx.x; k_ < 1024; k_ += 256) {              \
    float x_  = (k_ - 512) * 0.015625f;                           \
    float y0_ = gelu_f(x_);                                       \
    float y1_ = gelu_f(x_ + 0.015625f);                           \
    tab[k_] = make_float2(y0_, y1_ - y0_);                        \
  }                                                               \
  __syncthreads();

__device__ __forceinline__ half4 lo4(half8 v) {
  return __builtin_shufflevector(v, v, 0, 1, 2, 3);
}
__device__ __forceinline__ half4 hi4(half8 v) {
  return __builtin_shufflevector(v, v, 4, 5, 6, 7);
}

// W1 packs: K32 A-operand fragments (16x16x32): frag[(s*NT1+nt)*64+l][j] =
//   W[k = s*32 + (l>>4)*8 + j][n = nt*16 + (l&15)]
// W2 packs: K16 A-operand fragments (16x16x16) in nt-PAIRS (b128 loads):
//   frag[(ht*NP + np)*64+l][j] = W[k = ht*16 + (l>>4)*4 + (j&3)]
//                                 [n = (2np + (j>>2))*16 + (l&15)]
__global__ void pack_kernel(const float* __restrict__ cW1, const float* __restrict__ cb1,
                            const float* __restrict__ cW2, const float* __restrict__ cb2,
                            const float* __restrict__ vW1, const float* __restrict__ vb1,
                            const float* __restrict__ vW2, const float* __restrict__ vb2,
                            _Float16* __restrict__ w1c, _Float16* __restrict__ w2c,
                            _Float16* __restrict__ w1v, _Float16* __restrict__ w2v,
                            float* __restrict__ b1c, float* __restrict__ w96c,
                            float* __restrict__ b2c, float* __restrict__ b1v,
                            float* __restrict__ b2v)
{
  int id = blockIdx.x * 256 + threadIdx.x;
  const int S0 = KS1C * NT1C * 64;   // 4992  (half8)
  const int S1 = NT1C * 3 * 64;      // 4992  (half8 = paired half4)
  const int S2 = KS1V * NT1V * 64;   // 1664  (half8)
  const int S3 = NT1V * 2 * 64;      // 1664  (half8 = paired half4)
  if (id < S0) {
    int s = id / (NT1C * 64), rem = id % (NT1C * 64), nt = rem / 64, l = rem % 64;
    int q = l >> 4, n = nt * 16 + (l & 15);
    half8 v;
    #pragma unroll
    for (int j = 0; j < 8; ++j) {
      int k = s * 32 + q * 8 + j;
      float x = (n < 388) ? cW1[k * 388 + n] : 0.0f;
      v[j] = (_Float16)x;
    }
    *(half8*)(w1c + (size_t)id * 8) = v;
    return;
  }
  id -= S0;
  if (id < S1) {
    int ht = id / (3 * 64), rem = id % (3 * 64), np = rem / 64, l = rem % 64;
    int q = l >> 4, c = l & 15;
    half8 v;
    #pragma unroll
    for (int j = 0; j < 8; ++j) {
      int k = ht * 16 + q * 4 + (j & 3);
      int n = (2 * np + (j >> 2)) * 16 + c;
      float x = (k < 388) ? cW2[k * 96 + n] : 0.0f;
      v[j] = (_Float16)x;
    }
    *(half8*)(w2c + (size_t)id * 8) = v;
    return;
  }
  id -= S1;
  if (id < S2) {
    int s = id / (NT1V * 64), rem = id % (NT1V * 64), nt = rem / 64, l = rem % 64;
    int q = l >> 4, n = nt * 16 + (l & 15);
    half8 v;
    #pragma unroll
    for (int j = 0; j < 8; ++j) {
      int k = s * 32 + q * 8 + j;                        // row 48 = prior row
      float x = (k < 49 && n < 196) ? vW1[k * 196 + n] : 0.0f;
      v[j] = (_Float16)x;
    }
    *(half8*)(w1v + (size_t)id * 8) = v;
    return;
  }
  id -= S2;
  if (id < S3) {
    int ht = id / (2 * 64), rem = id % (2 * 64), np = rem / 64, l = rem % 64;
    int q = l >> 4, c = l & 15;
    half8 v;
    #pragma unroll
    for (int j = 0; j < 8; ++j) {
      int k = ht * 16 + q * 4 + (j & 3);
      int n = (2 * np + (j >> 2)) * 16 + c;
      float x = (k < 196 && n < 49) ? vW2[k * 49 + n] : 0.0f;
      v[j] = (_Float16)x;
    }
    *(half8*)(w2v + (size_t)id * 8) = v;
    return;
  }
  id -= S3;
  if (id < 416) { b1c[id]  = (id < 388) ? cb1[id] : 0.0f; return; }
  id -= 416;
  if (id < 416) { w96c[id] = (id < 388) ? cW1[96 * 388 + id] : 0.0f; return; }
  id -= 416;
  if (id < 96)  { b2c[id]  = cb2[id]; return; }
  id -= 96;
  if (id < 208) { b1v[id]  = (id < 196) ? vb1[id] : 0.0f; return; }
  id -= 208;
  if (id < 64)  { b2v[id]  = (id < 49) ? vb2[id] : 0.0f; return; }
}

__global__ void init_kernel(const int* __restrict__ perm, const float* __restrict__ prior,
                            _Float16* __restrict__ Mc)
{
  int t = blockIdx.x * 256 + threadIdx.x;   // t < BATCH*EDGE
  int b = t / EDGE, k = t - b * EDGE;
  int e = perm[k];
  _Float16* dst = Mc + ((size_t)b * EDGE + e) * 16;
  half8 z  = {0,0,0,0,0,0,0,0};
  half8 z0 = z;
  z0[0] = (_Float16)prior[k / 3];
  *(half8*)dst = z0;
  *(half8*)(dst + 8) = z;
}

// one ht-step of the check MLP (weights already in registers)
#define CSTEP(HT, WA0, WA1, WA2, WP0, WP1, WP2)                                       \
  {                                                                                   \
    floatx4 bia = *(const floatx4*)(b1  + (HT) * 16 + q * 4);                         \
    floatx4 wsg = *(const floatx4*)(w96 + (HT) * 16 + q * 4);                         \
    floatx4 a;                                                                        \
    _Pragma("unroll")                                                                 \
    for (int r = 0; r < 4; ++r) a[r] = fmaf(sg, wsg[r], bia[r]);                      \
    a = __builtin_amdgcn_mfma_f32_16x16x32_f16(WA0, mb[0], a, 0, 0, 0);               \
    a = __builtin_amdgcn_mfma_f32_16x16x32_f16(WA1, mb[1], a, 0, 0, 0);               \
    a = __builtin_amdgcn_mfma_f32_16x16x32_f16(WA2, mb[2], a, 0, 0, 0);               \
    half4 h;                                                                          \
    _Pragma("unroll")                                                                 \
    for (int r = 0; r < 4; ++r) h[r] = (_Float16)gelu_lut(tab, a[r]);                 \
    acc2[0] = __builtin_amdgcn_mfma_f32_16x16x16f16(lo4(WP0), h, acc2[0], 0, 0, 0);   \
    acc2[1] = __builtin_amdgcn_mfma_f32_16x16x16f16(hi4(WP0), h, acc2[1], 0, 0, 0);   \
    acc2[2] = __builtin_amdgcn_mfma_f32_16x16x16f16(lo4(WP1), h, acc2[2], 0, 0, 0);   \
    acc2[3] = __builtin_amdgcn_mfma_f32_16x16x16f16(hi4(WP1), h, acc2[3], 0, 0, 0);   \
    acc2[4] = __builtin_amdgcn_mfma_f32_16x16x16f16(lo4(WP2), h, acc2[4], 0, 0, 0);   \
    acc2[5] = __builtin_amdgcn_mfma_f32_16x16x16f16(hi4(WP2), h, acc2[5], 0, 0, 0);   \
  }

#define CLOADA(HT)                                                                    \
  a0A = W1f[(0 * NT1C + (HT)) * 64 + l];                                              \
  a1A = W1f[(1 * NT1C + (HT)) * 64 + l];                                              \
  a2A = W1f[(2 * NT1C + (HT)) * 64 + l];                                              \
  p0A = W2f[((HT) * 3 + 0) * 64 + l];                                                 \
  p1A = W2f[((HT) * 3 + 1) * 64 + l];                                                 \
  p2A = W2f[((HT) * 3 + 2) * 64 + l];

#define CLOADB(HT)                                                                    \
  a0B = W1f[(0 * NT1C + (HT)) * 64 + l];                                              \
  a1B = W1f[(1 * NT1C + (HT)) * 64 + l];                                              \
  a2B = W1f[(2 * NT1C + (HT)) * 64 + l];                                              \
  p0B = W2f[((HT) * 3 + 0) * 64 + l];                                                 \
  p1B = W2f[((HT) * 3 + 1) * 64 + l];                                                 \
  p2B = W2f[((HT) * 3 + 2) * 64 + l];

// Check-node MLP, 16 rows/wave, register-direct GEMM1 -> LUT-gelu -> GEMM2,
// with 2-deep double-buffered REGISTER PREFETCH of the weight stream.
// Round-4 lesson: VALU 55->32% with zero time change => the 52% idle is
// exposed L2 load latency (loads issued+consumed in the same iteration).
// Here buffer-B loads issue BEFORE buffer-A's compute: one full compute
// phase (~300+ cy of MFMA+gelu) covers each load's L2 latency.
__global__ __launch_bounds__(256, 4) void kernelC(
    const _Float16* __restrict__ Mc, const int* __restrict__ synd,
    _Float16* __restrict__ Yc,
    const _Float16* __restrict__ W1p, const _Float16* __restrict__ W2p,
    const float* __restrict__ b1, const float* __restrict__ w96,
    const float* __restrict__ b2)
{
  __shared__ float2 tab[1024];
  BUILD_TAB(tab)

  const int tid = threadIdx.x, w = tid >> 6, l = tid & 63;
  const int q = l >> 4, c = l & 15;
  const int r0 = blockIdx.x * 64 + w * 16;

  // Mc fragment (B-operand: lane holds batch-row n = l&15, k = q*8+j)
  half8 mb[3];
  const _Float16* Arow = Mc + (size_t)(r0 + c) * KC;
  #pragma unroll
  for (int ks = 0; ks < 3; ++ks)
    mb[ks] = *(const half8*)(Arow + ks * 32 + q * 8);
  const float sg = 1.0f - 2.0f * (float)synd[r0 + c];

  floatx4 acc2[6];
  #pragma unroll
  for (int nt = 0; nt < 6; ++nt)
    acc2[nt] = (floatx4){0.f, 0.f, 0.f, 0.f};

  const half8* W1f = (const half8*)W1p;
  const half8* W2f = (const half8*)W2p;

  half8 a0A, a1A, a2A, p0A, p1A, p2A;
  half8 a0B, a1B, a2B, p0B, p1B, p2B;
  CLOADA(0)

  #pragma unroll 1
  for (int i = 0; i < 13; ++i) {
    const int h1 = 2 * i + 1;
    CLOADB(h1)                       // issue next-tile loads first
    CSTEP(2 * i, a0A, a1A, a2A, p0A, p1A, p2A)
    const int h2 = (2 * i + 2 < NT1C) ? 2 * i + 2 : NT1C - 1;  // last: harmless re-read
    CLOADA(h2)
    CSTEP(h1, a0B, a1B, a2B, p0B, p1B, p2B)
  }

  const size_t row = (size_t)(r0 + c);
  #pragma unroll
  for (int nt = 0; nt < 6; ++nt) {
    floatx4 bia = *(const floatx4*)(b2 + nt * 16 + q * 4);
    half4 yy;
    #pragma unroll
    for (int r = 0; r < 4; ++r)
      yy[r] = (_Float16)((acc2[nt][r] + bia[r]) * sg);
    *(half4*)(Yc + row * 96 + nt * 16 + q * 4) = yy;
  }
}

// one ht-step of the var MLP (weights already in registers)
#define VSTEP(HT, WA0, WA1, WP0, WP1)                                                 \
  {                                                                                   \
    floatx4 a = *(const floatx4*)(b1 + (HT) * 16 + q * 4);                            \
    a = __builtin_amdgcn_mfma_f32_16x16x32_f16(WA0, mb[0], a, 0, 0, 0);               \
    a = __builtin_amdgcn_mfma_f32_16x16x32_f16(WA1, mb[1], a, 0, 0, 0);               \
    half4 h;                                                                          \
    _Pragma("unroll")                                                                 \
    for (int r = 0; r < 4; ++r) h[r] = (_Float16)gelu_lut(tab, a[r]);                 \
    acc2[0] = __builtin_amdgcn_mfma_f32_16x16x16f16(lo4(WP0), h, acc2[0], 0, 0, 0);   \
    acc2[1] = __builtin_amdgcn_mfma_f32_16x16x16f16(hi4(WP0), h, acc2[1], 0, 0, 0);   \
    acc2[2] = __builtin_amdgcn_mfma_f32_16x16x16f16(lo4(WP1), h, acc2[2], 0, 0, 0);   \
    acc2[3] = __builtin_amdgcn_mfma_f32_16x16x16f16(hi4(WP1), h, acc2[3], 0, 0, 0);   \
  }

#define VLOADA(HT)                                                                    \
  a0A = W1f[(0 * NT1V + (HT)) * 64 + l];                                              \
  a1A = W1f[(1 * NT1V + (HT)) * 64 + l];                                              \
  p0A = W2f[((HT) * 2 + 0) * 64 + l];                                                 \
  p1A = W2f[((HT) * 2 + 1) * 64 + l];

#define VLOADB(HT)                                                                    \
  a0B = W1f[(0 * NT1V + (HT)) * 64 + l];                                              \
  a1B = W1f[(1 * NT1V + (HT)) * 64 + l];                                              \
  p0B = W2f[((HT) * 2 + 0) * 64 + l];                                                 \
  p1B = W2f[((HT) * 2 + 1) * 64 + l];

// Variable-node MLP, 16 vars/wave, LUT-gelu, bias as GEMM1 C-operand init,
// same 2-deep register prefetch (NT1V=13 odd: 6 pairs + tail).
__global__ __launch_bounds__(256, 6) void kernelV(
    const _Float16* __restrict__ Yc, const int* __restrict__ perm,
    const float* __restrict__ prior,
    _Float16* __restrict__ Mc, float* __restrict__ outp,
    const _Float16* __restrict__ W1p, const _Float16* __restrict__ W2p,
    const float* __restrict__ b1, const float* __restrict__ b2)
{
  __shared__ float2 tab[1024];
  BUILD_TAB(tab)

  const int tid = threadIdx.x, w = tid >> 6, l = tid & 63;
  const int q = l >> 4, c = l & 15;
  const int r0 = blockIdx.x * 64 + w * 16;
  const int b  = r0 >> 10;
  const int v0 = r0 & 1023;
  const size_t yb = (size_t)b * EDGE;

  // Xv^T fragment: lane holds var-row n = l&15, k = q*8+j (K=64: 48 msgs + prior + pad)
  half8 mb[2];
  {
    int v = v0 + c;
    int e0 = perm[3 * v + (q >> 1)];
    mb[0] = *(const half8*)(Yc + (yb + e0) * 16 + (q & 1) * 8);
    half8 m1 = {0,0,0,0,0,0,0,0};
    if (q < 2) {
      int e2 = perm[3 * v + 2];
      m1 = *(const half8*)(Yc + (yb + e2) * 16 + q * 8);
    } else if (q == 2) {
      m1[0] = (_Float16)prior[v];
    }
    mb[1] = m1;
  }

  floatx4 acc2[4];
  #pragma unroll
  for (int nt = 0; nt < 4; ++nt)
    acc2[nt] = (floatx4){0.f, 0.f, 0.f, 0.f};

  const half8* W1f = (const half8*)W1p;
  const half8* W2f = (const half8*)W2p;

  half8 a0A, a1A, p0A, p1A;
  half8 a0B, a1B, p0B, p1B;
  VLOADA(0)

  #pragma unroll 1
  for (int i = 0; i < 6; ++i) {
    const int h1 = 2 * i + 1;
    VLOADB(h1)
    VSTEP(2 * i, a0A, a1A, p0A, p1A)
    VLOADA(2 * i + 2)
    VSTEP(h1, a0B, a1B, p0B, p1B)
  }
  VSTEP(12, a0A, a1A, p0A, p1A)

  const float bllr = b2[48];
  {
    int v = v0 + c;
    #pragma unroll
    for (int nt = 0; nt < 3; ++nt) {
      int pe = perm[3 * v + nt];
      floatx4 bia = *(const floatx4*)(b2 + nt * 16 + q * 4);
      half4 yy;
      #pragma unroll
      for (int r = 0; r < 4; ++r)
        yy[r] = (_Float16)(acc2[nt][r] + bia[r]);
      *(half4*)(Mc + (yb + pe) * 16 + q * 4) = yy;
    }
    if (q == 0)
      outp[r0 + c] = acc2[3][0] + bllr;
  }
}

extern "C" void kernel_launch(void* const* d_in, const int* in_sizes, int n_in,
                              void* d_out, int out_size, void* d_ws, size_t ws_size,
                              hipStream_t stream)
{
  const int*   synd  = (const int*)d_in[0];
  const float* prior = (const float*)d_in[2];
  const int*   perm  = (const int*)d_in[3];
  const float* cW1 = (const float*)d_in[4];
  const float* cb1 = (const float*)d_in[5];
  const float* cW2 = (const float*)d_in[6];
  const float* cb2 = (const float*)d_in[7];
  const float* vW1 = (const float*)d_in[8];
  const float* vb1 = (const float*)d_in[9];
  const float* vW2 = (const float*)d_in[10];
  const float* vb2 = (const float*)d_in[11];
  float* outp = (float*)d_out;
  const int T = out_size / (BATCH * NVAR);

  char* p = (char*)d_ws;
  _Float16* Mc  = (_Float16*)p; p += (size_t)BATCH * EDGE * 16 * 2;
  _Float16* Yc  = (_Float16*)p; p += (size_t)BATCH * EDGE * 16 * 2;
  _Float16* w1c = (_Float16*)p; p += (size_t)KS1C * NT1C * 64 * 8 * 2;
  _Float16* w2c = (_Float16*)p; p += (size_t)NT1C * 3 * 64 * 8 * 2;
  _Float16* w1v = (_Float16*)p; p += (size_t)KS1V * NT1V * 64 * 8 * 2;
  _Float16* w2v = (_Float16*)p; p += (size_t)NT1V * 2 * 64 * 8 * 2;
  float* b1c  = (float*)p; p += 416 * 4;
  float* w96c = (float*)p; p += 416 * 4;
  float* b2c  = (float*)p; p += 96 * 4;
  float* b1v  = (float*)p; p += 208 * 4;
  float* b2v  = (float*)p; p += 64 * 4;

  const int packN = KS1C * NT1C * 64 + NT1C * 3 * 64 + KS1V * NT1V * 64 +
                    NT1V * 2 * 64 + 416 + 416 + 96 + 208 + 64;   // 14512
  pack_kernel<<<(packN + 255) / 256, 256, 0, stream>>>(
      cW1, cb1, cW2, cb2, vW1, vb1, vW2, vb2,
      w1c, w2c, w1v, w2v, b1c, w96c, b2c, b1v, b2v);
  init_kernel<<<(BATCH * EDGE) / 256, 256, 0, stream>>>(perm, prior, Mc);

  for (int t = 0; t < T; ++t) {
    kernelC<<<(BATCH * NCHK) / 64, 256, 0, stream>>>(
        Mc, synd, Yc, w1c, w2c, b1c, w96c, b2c);
    kernelV<<<(BATCH * NVAR) / 64, 256, 0, stream>>>(
        Yc, perm, prior, Mc, outp + (size_t)t * BATCH * NVAR, w1v, w2v, b1v, b2v);
  }
}

// Round 7
// 615.426 us; speedup vs baseline: 6.6618x; 1.0147x over previous
//
#include <hip/hip_runtime.h>
#include <cstdint>
#include <cstddef>

typedef _Float16 half8 __attribute__((ext_vector_type(8)));
typedef _Float16 half4 __attribute__((ext_vector_type(4)));
typedef float floatx4 __attribute__((ext_vector_type(4)));

#define BATCH 256
#define NCHK 512
#define NVAR 1024
#define EDGE 3072

// ---- check MLP tiling ----
#define KC    96
#define NT1C  26     // hidden 388 -> 416 -> 26 col-tiles of 16
#define KS1C  3      // GEMM1 K = 96 -> 3 chunks of 32
#define NT2C  6      // out 96 -> 6 tiles of 16 (3 b128 pairs)
// ---- var MLP tiling ----
#define NT1V  13     // hidden 196 -> 208 -> 13 col-tiles of 16
#define KS1V  2      // GEMM1 K 49 -> 64 -> 2 chunks of 32
#define NT2V  4      // out 49 -> 64 -> 4 tiles of 16 (2 b128 pairs)

__device__ __forceinline__ float gelu_f(float x) {
  // exact gelu via A&S 7.1.26 erf approx, |err(erf)| < 1.5e-7 (table builder only)
  float ax = fabsf(x) * 0.70710678118654752440f;
  float t  = 1.0f / fmaf(0.3275911f, ax, 1.0f);
  float p  = t * (0.254829592f + t * (-0.284496736f + t * (1.421413741f +
             t * (-1.453152027f + t * 1.061405429f))));
  float e  = __expf(-ax * ax);
  float erfv = fmaf(-p, e, 1.0f);
  float s  = copysignf(erfv, x);
  float hx = 0.5f * x;
  return fmaf(hx, s, hx);
}

// PWL gelu: 1024 segments over [-8,8], node+slope in LDS (float2, ds_read_b64).
// |err| <= w^2/8 * max|gelu''| = (1/64)^2/8 * 0.8 ~ 2.4e-5 absolute.
// Out of range: h += max(t-tc,0)/64 -> exact h=x for x>8; h~0 for x<-8.
__device__ __forceinline__ float gelu_lut(const float2* __restrict__ tab, float x) {
  float t  = fmaf(x, 64.0f, 512.0f);
  float tc = fminf(fmaxf(t, 0.0f), 1023.0f);
  float tf = __builtin_truncf(tc);
  float fr = tc - tf;
  int idx  = (int)tf;
  float2 ns = tab[idx];
  float h  = fmaf(fr, ns.y, ns.x);
  return fmaf(fmaxf(t - tc, 0.0f), 0.015625f, h);
}

#define BUILD_TAB(tab)                                            \
  for (int k_ = threadIdx.x; k_ < 1024; k_ += 256) {              \
    float x_  = (k_ - 512) * 0.015625f;                           \
    float y0_ = gelu_f(x_);                                       \
    float y1_ = gelu_f(x_ + 0.015625f);                           \
    tab[k_] = make_float2(y0_, y1_ - y0_);                        \
  }                                                               \
  __syncthreads();

__device__ __forceinline__ half4 lo4(half8 v) {
  return __builtin_shufflevector(v, v, 0, 1, 2, 3);
}
__device__ __forceinline__ half4 hi4(half8 v) {
  return __builtin_shufflevector(v, v, 4, 5, 6, 7);
}

// W1 packs: K32 A-operand fragments (16x16x32): frag[(s*NT1+nt)*64+l][j] =
//   W[k = s*32 + (l>>4)*8 + j][n = nt*16 + (l&15)]
// W2 packs: K16 A-operand fragments (16x16x16) in nt-PAIRS (b128 loads):
//   frag[(ht*NP + np)*64+l][j] = W[k = ht*16 + (l>>4)*4 + (j&3)]
//                                 [n = (2np + (j>>2))*16 + (l&15)]
// Bias combos: bwp = b1 + w96, bwm = b1 - w96 (fp32; fl(b1±w96) ==
//   fmaf(±1, w96, b1) bitwise) — lets kernelC prefetch ONE C-init vector.
__global__ void pack_kernel(const float* __restrict__ cW1, const float* __restrict__ cb1,
                            const float* __restrict__ cW2, const float* __restrict__ cb2,
                            const float* __restrict__ vW1, const float* __restrict__ vb1,
                            const float* __restrict__ vW2, const float* __restrict__ vb2,
                            _Float16* __restrict__ w1c, _Float16* __restrict__ w2c,
                            _Float16* __restrict__ w1v, _Float16* __restrict__ w2v,
                            float* __restrict__ bwp, float* __restrict__ bwm,
                            float* __restrict__ b2c, float* __restrict__ b1v,
                            float* __restrict__ b2v)
{
  int id = blockIdx.x * 256 + threadIdx.x;
  const int S0 = KS1C * NT1C * 64;   // 4992  (half8)
  const int S1 = NT1C * 3 * 64;      // 4992  (half8 = paired half4)
  const int S2 = KS1V * NT1V * 64;   // 1664  (half8)
  const int S3 = NT1V * 2 * 64;      // 1664  (half8 = paired half4)
  if (id < S0) {
    int s = id / (NT1C * 64), rem = id % (NT1C * 64), nt = rem / 64, l = rem % 64;
    int q = l >> 4, n = nt * 16 + (l & 15);
    half8 v;
    #pragma unroll
    for (int j = 0; j < 8; ++j) {
      int k = s * 32 + q * 8 + j;
      float x = (n < 388) ? cW1[k * 388 + n] : 0.0f;
      v[j] = (_Float16)x;
    }
    *(half8*)(w1c + (size_t)id * 8) = v;
    return;
  }
  id -= S0;
  if (id < S1) {
    int ht = id / (3 * 64), rem = id % (3 * 64), np = rem / 64, l = rem % 64;
    int q = l >> 4, c = l & 15;
    half8 v;
    #pragma unroll
    for (int j = 0; j < 8; ++j) {
      int k = ht * 16 + q * 4 + (j & 3);
      int n = (2 * np + (j >> 2)) * 16 + c;
      float x = (k < 388) ? cW2[k * 96 + n] : 0.0f;
      v[j] = (_Float16)x;
    }
    *(half8*)(w2c + (size_t)id * 8) = v;
    return;
  }
  id -= S1;
  if (id < S2) {
    int s = id / (NT1V * 64), rem = id % (NT1V * 64), nt = rem / 64, l = rem % 64;
    int q = l >> 4, n = nt * 16 + (l & 15);
    half8 v;
    #pragma unroll
    for (int j = 0; j < 8; ++j) {
      int k = s * 32 + q * 8 + j;                        // row 48 = prior row
      float x = (k < 49 && n < 196) ? vW1[k * 196 + n] : 0.0f;
      v[j] = (_Float16)x;
    }
    *(half8*)(w1v + (size_t)id * 8) = v;
    return;
  }
  id -= S2;
  if (id < S3) {
    int ht = id / (2 * 64), rem = id % (2 * 64), np = rem / 64, l = rem % 64;
    int q = l >> 4, c = l & 15;
    half8 v;
    #pragma unroll
    for (int j = 0; j < 8; ++j) {
      int k = ht * 16 + q * 4 + (j & 3);
      int n = (2 * np + (j >> 2)) * 16 + c;
      float x = (k < 196 && n < 49) ? vW2[k * 49 + n] : 0.0f;
      v[j] = (_Float16)x;
    }
    *(half8*)(w2v + (size_t)id * 8) = v;
    return;
  }
  id -= S3;
  if (id < 416) {
    float b = (id < 388) ? cb1[id] : 0.0f;
    float wv = (id < 388) ? cW1[96 * 388 + id] : 0.0f;
    bwp[id] = b + wv;
    return;
  }
  id -= 416;
  if (id < 416) {
    float b = (id < 388) ? cb1[id] : 0.0f;
    float wv = (id < 388) ? cW1[96 * 388 + id] : 0.0f;
    bwm[id] = b - wv;
    return;
  }
  id -= 416;
  if (id < 96)  { b2c[id]  = cb2[id]; return; }
  id -= 96;
  if (id < 208) { b1v[id]  = (id < 196) ? vb1[id] : 0.0f; return; }
  id -= 208;
  if (id < 64)  { b2v[id]  = (id < 49) ? vb2[id] : 0.0f; return; }
}

__global__ void init_kernel(const int* __restrict__ perm, const float* __restrict__ prior,
                            _Float16* __restrict__ Mc)
{
  int t = blockIdx.x * 256 + threadIdx.x;   // t < BATCH*EDGE
  int b = t / EDGE, k = t - b * EDGE;
  int e = perm[k];
  _Float16* dst = Mc + ((size_t)b * EDGE + e) * 16;
  half8 z  = {0,0,0,0,0,0,0,0};
  half8 z0 = z;
  z0[0] = (_Float16)prior[k / 3];
  *(half8*)dst = z0;
  *(half8*)(dst + 8) = z;
}

// one ht-step of the check MLP (weights AND C-init already in registers —
// round-6 lesson: any global load consumed in its own iteration forces an
// in-order vmcnt drain of the just-issued prefetch, defeating it)
#define CSTEP(WA0, WA1, WA2, WP0, WP1, WP2, WI)                                       \
  {                                                                                   \
    floatx4 a = WI;                                                                   \
    a = __builtin_amdgcn_mfma_f32_16x16x32_f16(WA0, mb[0], a, 0, 0, 0);               \
    a = __builtin_amdgcn_mfma_f32_16x16x32_f16(WA1, mb[1], a, 0, 0, 0);               \
    a = __builtin_amdgcn_mfma_f32_16x16x32_f16(WA2, mb[2], a, 0, 0, 0);               \
    half4 h;                                                                          \
    _Pragma("unroll")                                                                 \
    for (int r = 0; r < 4; ++r) h[r] = (_Float16)gelu_lut(tab, a[r]);                 \
    acc2[0] = __builtin_amdgcn_mfma_f32_16x16x16f16(lo4(WP0), h, acc2[0], 0, 0, 0);   \
    acc2[1] = __builtin_amdgcn_mfma_f32_16x16x16f16(hi4(WP0), h, acc2[1], 0, 0, 0);   \
    acc2[2] = __builtin_amdgcn_mfma_f32_16x16x16f16(lo4(WP1), h, acc2[2], 0, 0, 0);   \
    acc2[3] = __builtin_amdgcn_mfma_f32_16x16x16f16(hi4(WP1), h, acc2[3], 0, 0, 0);   \
    acc2[4] = __builtin_amdgcn_mfma_f32_16x16x16f16(lo4(WP2), h, acc2[4], 0, 0, 0);   \
    acc2[5] = __builtin_amdgcn_mfma_f32_16x16x16f16(hi4(WP2), h, acc2[5], 0, 0, 0);   \
  }

#define CLOADA(HT)                                                                    \
  a0A = W1f[(0 * NT1C + (HT)) * 64 + l];                                              \
  a1A = W1f[(1 * NT1C + (HT)) * 64 + l];                                              \
  a2A = W1f[(2 * NT1C + (HT)) * 64 + l];                                              \
  p0A = W2f[((HT) * 3 + 0) * 64 + l];                                                 \
  p1A = W2f[((HT) * 3 + 1) * 64 + l];                                                 \
  p2A = W2f[((HT) * 3 + 2) * 64 + l];                                                 \
  iA  = *(const floatx4*)(bw + (HT) * 16 + q * 4);

#define CLOADB(HT)                                                                    \
  a0B = W1f[(0 * NT1C + (HT)) * 64 + l];                                              \
  a1B = W1f[(1 * NT1C + (HT)) * 64 + l];                                              \
  a2B = W1f[(2 * NT1C + (HT)) * 64 + l];                                              \
  p0B = W2f[((HT) * 3 + 0) * 64 + l];                                                 \
  p1B = W2f[((HT) * 3 + 1) * 64 + l];                                                 \
  p2B = W2f[((HT) * 3 + 2) * 64 + l];                                                 \
  iB  = *(const floatx4*)(bw + (HT) * 16 + q * 4);

// Check-node MLP, 16 rows/wave, register-direct GEMM1 -> LUT-gelu -> GEMM2,
// 2-deep register prefetch covering the ENTIRE per-iteration load set
// (6 weight frags + 1 C-init vector). Steady state: issue 7 loads for tile
// i+1, consume tile i behind a counted vmcnt — never a drain.
__global__ __launch_bounds__(256, 4) void kernelC(
    const _Float16* __restrict__ Mc, const int* __restrict__ synd,
    _Float16* __restrict__ Yc,
    const _Float16* __restrict__ W1p, const _Float16* __restrict__ W2p,
    const float* __restrict__ bwp, const float* __restrict__ bwm,
    const float* __restrict__ b2)
{
  __shared__ float2 tab[1024];
  BUILD_TAB(tab)

  const int tid = threadIdx.x, w = tid >> 6, l = tid & 63;
  const int q = l >> 4, c = l & 15;
  const int r0 = blockIdx.x * 64 + w * 16;

  // Mc fragment (B-operand: lane holds batch-row n = l&15, k = q*8+j)
  half8 mb[3];
  const _Float16* Arow = Mc + (size_t)(r0 + c) * KC;
  #pragma unroll
  for (int ks = 0; ks < 3; ++ks)
    mb[ks] = *(const half8*)(Arow + ks * 32 + q * 8);
  const float sg = 1.0f - 2.0f * (float)synd[r0 + c];
  const float* bw = (sg > 0.0f) ? bwp : bwm;   // loop-invariant C-init stream

  floatx4 acc2[6];
  #pragma unroll
  for (int nt = 0; nt < 6; ++nt)
    acc2[nt] = (floatx4){0.f, 0.f, 0.f, 0.f};

  const half8* W1f = (const half8*)W1p;
  const half8* W2f = (const half8*)W2p;

  half8 a0A, a1A, a2A, p0A, p1A, p2A;
  half8 a0B, a1B, a2B, p0B, p1B, p2B;
  floatx4 iA, iB;
  CLOADA(0)

  #pragma unroll 1
  for (int i = 0; i < 13; ++i) {
    const int h1 = 2 * i + 1;
    CLOADB(h1)                       // issue next-tile loads first
    CSTEP(a0A, a1A, a2A, p0A, p1A, p2A, iA)
    const int h2 = (2 * i + 2 < NT1C) ? 2 * i + 2 : NT1C - 1;  // last: harmless re-read
    CLOADA(h2)
    CSTEP(a0B, a1B, a2B, p0B, p1B, p2B, iB)
  }

  const size_t row = (size_t)(r0 + c);
  #pragma unroll
  for (int nt = 0; nt < 6; ++nt) {
    floatx4 bia = *(const floatx4*)(b2 + nt * 16 + q * 4);
    half4 yy;
    #pragma unroll
    for (int r = 0; r < 4; ++r)
      yy[r] = (_Float16)((acc2[nt][r] + bia[r]) * sg);
    *(half4*)(Yc + row * 96 + nt * 16 + q * 4) = yy;
  }
}

// one ht-step of the var MLP (weights + C-init in registers)
#define VSTEP(WA0, WA1, WP0, WP1, WI)                                                 \
  {                                                                                   \
    floatx4 a = WI;                                                                   \
    a = __builtin_amdgcn_mfma_f32_16x16x32_f16(WA0, mb[0], a, 0, 0, 0);               \
    a = __builtin_amdgcn_mfma_f32_16x16x32_f16(WA1, mb[1], a, 0, 0, 0);               \
    half4 h;                                                                          \
    _Pragma("unroll")                                                                 \
    for (int r = 0; r < 4; ++r) h[r] = (_Float16)gelu_lut(tab, a[r]);                 \
    acc2[0] = __builtin_amdgcn_mfma_f32_16x16x16f16(lo4(WP0), h, acc2[0], 0, 0, 0);   \
    acc2[1] = __builtin_amdgcn_mfma_f32_16x16x16f16(hi4(WP0), h, acc2[1], 0, 0, 0);   \
    acc2[2] = __builtin_amdgcn_mfma_f32_16x16x16f16(lo4(WP1), h, acc2[2], 0, 0, 0);   \
    acc2[3] = __builtin_amdgcn_mfma_f32_16x16x16f16(hi4(WP1), h, acc2[3], 0, 0, 0);   \
  }

#define VLOADA(HT)                                                                    \
  a0A = W1f[(0 * NT1V + (HT)) * 64 + l];                                              \
  a1A = W1f[(1 * NT1V + (HT)) * 64 + l];                                              \
  p0A = W2f[((HT) * 2 + 0) * 64 + l];                                                 \
  p1A = W2f[((HT) * 2 + 1) * 64 + l];                                                 \
  iA  = *(const floatx4*)(b1 + (HT) * 16 + q * 4);

#define VLOADB(HT)                                                                    \
  a0B = W1f[(0 * NT1V + (HT)) * 64 + l];                                              \
  a1B = W1f[(1 * NT1V + (HT)) * 64 + l];                                              \
  p0B = W2f[((HT) * 2 + 0) * 64 + l];                                                 \
  p1B = W2f[((HT) * 2 + 1) * 64 + l];                                                 \
  iB  = *(const floatx4*)(b1 + (HT) * 16 + q * 4);

// Variable-node MLP, 16 vars/wave, LUT-gelu, full-prefetch rotation
// (NT1V=13 odd: 6 pairs + tail).
__global__ __launch_bounds__(256, 6) void kernelV(
    const _Float16* __restrict__ Yc, const int* __restrict__ perm,
    const float* __restrict__ prior,
    _Float16* __restrict__ Mc, float* __restrict__ outp,
    const _Float16* __restrict__ W1p, const _Float16* __restrict__ W2p,
    const float* __restrict__ b1, const float* __restrict__ b2)
{
  __shared__ float2 tab[1024];
  BUILD_TAB(tab)

  const int tid = threadIdx.x, w = tid >> 6, l = tid & 63;
  const int q = l >> 4, c = l & 15;
  const int r0 = blockIdx.x * 64 + w * 16;
  const int b  = r0 >> 10;
  const int v0 = r0 & 1023;
  const size_t yb = (size_t)b * EDGE;

  // Xv^T fragment: lane holds var-row n = l&15, k = q*8+j (K=64: 48 msgs + prior + pad)
  half8 mb[2];
  {
    int v = v0 + c;
    int e0 = perm[3 * v + (q >> 1)];
    mb[0] = *(const half8*)(Yc + (yb + e0) * 16 + (q & 1) * 8);
    half8 m1 = {0,0,0,0,0,0,0,0};
    if (q < 2) {
      int e2 = perm[3 * v + 2];
      m1 = *(const half8*)(Yc + (yb + e2) * 16 + q * 8);
    } else if (q == 2) {
      m1[0] = (_Float16)prior[v];
    }
    mb[1] = m1;
  }

  floatx4 acc2[4];
  #pragma unroll
  for (int nt = 0; nt < 4; ++nt)
    acc2[nt] = (floatx4){0.f, 0.f, 0.f, 0.f};

  const half8* W1f = (const half8*)W1p;
  const half8* W2f = (const half8*)W2p;

  half8 a0A, a1A, p0A, p1A;
  half8 a0B, a1B, p0B, p1B;
  floatx4 iA, iB;
  VLOADA(0)

  #pragma unroll 1
  for (int i = 0; i < 6; ++i) {
    const int h1 = 2 * i + 1;
    VLOADB(h1)
    VSTEP(a0A, a1A, p0A, p1A, iA)
    VLOADA(2 * i + 2)
    VSTEP(a0B, a1B, p0B, p1B, iB)
  }
  VSTEP(a0A, a1A, p0A, p1A, iA)      // ht = 12 (loaded by VLOADA at i=5)

  const float bllr = b2[48];
  {
    int v = v0 + c;
    #pragma unroll
    for (int nt = 0; nt < 3; ++nt) {
      int pe = perm[3 * v + nt];
      floatx4 bia = *(const floatx4*)(b2 + nt * 16 + q * 4);
      half4 yy;
      #pragma unroll
      for (int r = 0; r < 4; ++r)
        yy[r] = (_Float16)(acc2[nt][r] + bia[r]);
      *(half4*)(Mc + (yb + pe) * 16 + q * 4) = yy;
    }
    if (q == 0)
      outp[r0 + c] = acc2[3][0] + bllr;
  }
}

extern "C" void kernel_launch(void* const* d_in, const int* in_sizes, int n_in,
                              void* d_out, int out_size, void* d_ws, size_t ws_size,
                              hipStream_t stream)
{
  const int*   synd  = (const int*)d_in[0];
  const float* prior = (const float*)d_in[2];
  const int*   perm  = (const int*)d_in[3];
  const float* cW1 = (const float*)d_in[4];
  const float* cb1 = (const float*)d_in[5];
  const float* cW2 = (const float*)d_in[6];
  const float* cb2 = (const float*)d_in[7];
  const float* vW1 = (const float*)d_in[8];
  const float* vb1 = (const float*)d_in[9];
  const float* vW2 = (const float*)d_in[10];
  const float* vb2 = (const float*)d_in[11];
  float* outp = (float*)d_out;
  const int T = out_size / (BATCH * NVAR);

  char* p = (char*)d_ws;
  _Float16* Mc  = (_Float16*)p; p += (size_t)BATCH * EDGE * 16 * 2;
  _Float16* Yc  = (_Float16*)p; p += (size_t)BATCH * EDGE * 16 * 2;
  _Float16* w1c = (_Float16*)p; p += (size_t)KS1C * NT1C * 64 * 8 * 2;
  _Float16* w2c = (_Float16*)p; p += (size_t)NT1C * 3 * 64 * 8 * 2;
  _Float16* w1v = (_Float16*)p; p += (size_t)KS1V * NT1V * 64 * 8 * 2;
  _Float16* w2v = (_Float16*)p; p += (size_t)NT1V * 2 * 64 * 8 * 2;
  float* bwp  = (float*)p; p += 416 * 4;
  float* bwm  = (float*)p; p += 416 * 4;
  float* b2c  = (float*)p; p += 96 * 4;
  float* b1v  = (float*)p; p += 208 * 4;
  float* b2v  = (float*)p; p += 64 * 4;

  const int packN = KS1C * NT1C * 64 + NT1C * 3 * 64 + KS1V * NT1V * 64 +
                    NT1V * 2 * 64 + 416 + 416 + 96 + 208 + 64;   // 14512
  pack_kernel<<<(packN + 255) / 256, 256, 0, stream>>>(
      cW1, cb1, cW2, cb2, vW1, vb1, vW2, vb2,
      w1c, w2c, w1v, w2v, bwp, bwm, b2c, b1v, b2v);
  init_kernel<<<(BATCH * EDGE) / 256, 256, 0, stream>>>(perm, prior, Mc);

  for (int t = 0; t < T; ++t) {
    kernelC<<<(BATCH * NCHK) / 64, 256, 0, stream>>>(
        Mc, synd, Yc, w1c, w2c, bwp, bwm, b2c);
    kernelV<<<(BATCH * NVAR) / 64, 256, 0, stream>>>(
        Yc, perm, prior, Mc, outp + (size_t)t * BATCH * NVAR, w1v, w2v, b1v, b2v);
  }
}